// Round 2
// baseline (925.279 us; speedup 1.0000x reference)
//
#include <hip/hip_runtime.h>

// Temporal GraphSAGE, P=4 periods, C=128, L=2 (reference constants).
// R7: wave-aggregated compk. R6's per-thread atomicAdd-with-return onto 4
// counters serialized (145 us, 0.2% busy). Now: __ballot per wave, one
// atomicAdd per wave per period, __shfl broadcast + popcll prefix for slots.
// gemm: LDS-staged weight panel + full A-fragment prefetch (unchanged from R6).

#define CD 128

typedef __attribute__((ext_vector_type(8))) short s16x8;
typedef __attribute__((ext_vector_type(4))) float f32x4;

static __device__ __forceinline__ unsigned short f2bf(float f) {
  unsigned u = __float_as_uint(f);
  u += 0x7FFF + ((u >> 16) & 1);   // round-to-nearest-even
  return (unsigned short)(u >> 16);
}
static __device__ __forceinline__ float bf2f(unsigned us) {
  return __uint_as_float(us << 16);
}

// ---- histogram: per-(period,dst) degree + involved bitmask ----
__global__ __launch_bounds__(256) void histk(const int* __restrict__ ntime,
    const int* __restrict__ eidx, int* __restrict__ deg_pd, int* __restrict__ involved,
    const int* __restrict__ minp, const int* __restrict__ up, int N, int E) {
  int e = blockIdx.x * 256 + threadIdx.x;
  if (e >= E) return;
  int s = eidx[e], d = eidx[E + e];
  int ts = ntime[s], td = ntime[d];
  int m = ts > td ? ts : td;
  int p = (m - minp[0]) / up[0];
  atomicAdd(&deg_pd[p * N + d], 1);
  atomicOr(&involved[s], 1 << p);
  atomicOr(&involved[d], 1 << p);
}

// ---- per-period compaction of involved nodes (wave-aggregated atomics) ----
__global__ __launch_bounds__(256) void compk(const int* __restrict__ involved,
    int* __restrict__ nlist, int* __restrict__ ncnt, int N) {
  int i = blockIdx.x * 256 + threadIdx.x;
  int bits = (i < N) ? involved[i] : 0;   // no early return: keep wave intact
  int lane = threadIdx.x & 63;
  unsigned long long lanes_below = (lane == 0) ? 0ull : ((~0ull) >> (64 - lane));
#pragma unroll
  for (int p = 0; p < 4; ++p) {
    bool pred = (bits >> p) & 1;
    unsigned long long m = __ballot(pred);
    if (m == 0ull) continue;               // wave-uniform
    int c = __popcll(m);
    int leader = __ffsll((unsigned long long)m) - 1;
    int base = 0;
    if (lane == leader) base = atomicAdd(&ncnt[p], c);
    base = __shfl(base, leader, 64);
    if (pred) nlist[p * N + base + __popcll(m & lanes_below)] = i;
  }
}

// ---- exclusive scan (3-phase) ----
__global__ __launch_bounds__(256) void scan1(const int* __restrict__ in,
    int* __restrict__ out, int* __restrict__ bsums, int M) {
  __shared__ int lds[256];
  int tid = threadIdx.x;
  int base = blockIdx.x * 1024 + tid * 4;
  int v0 = base + 0 < M ? in[base + 0] : 0;
  int v1 = base + 1 < M ? in[base + 1] : 0;
  int v2 = base + 2 < M ? in[base + 2] : 0;
  int v3 = base + 3 < M ? in[base + 3] : 0;
  int s = v0 + v1 + v2 + v3;
  lds[tid] = s;
  __syncthreads();
  for (int off = 1; off < 256; off <<= 1) {
    int t = tid >= off ? lds[tid - off] : 0;
    __syncthreads();
    lds[tid] += t;
    __syncthreads();
  }
  int run = lds[tid] - s;
  if (base + 0 < M) out[base + 0] = run; run += v0;
  if (base + 1 < M) out[base + 1] = run; run += v1;
  if (base + 2 < M) out[base + 2] = run; run += v2;
  if (base + 3 < M) out[base + 3] = run;
  if (tid == 255) bsums[blockIdx.x] = lds[255];
}

__global__ __launch_bounds__(256) void scan2(int* __restrict__ b, int M) {
  __shared__ int lds[256];
  int tid = threadIdx.x;
  int base = tid * 4;
  int v0 = base + 0 < M ? b[base + 0] : 0;
  int v1 = base + 1 < M ? b[base + 1] : 0;
  int v2 = base + 2 < M ? b[base + 2] : 0;
  int v3 = base + 3 < M ? b[base + 3] : 0;
  int s = v0 + v1 + v2 + v3;
  lds[tid] = s;
  __syncthreads();
  for (int off = 1; off < 256; off <<= 1) {
    int t = tid >= off ? lds[tid - off] : 0;
    __syncthreads();
    lds[tid] += t;
    __syncthreads();
  }
  int run = lds[tid] - s;
  if (base + 0 < M) b[base + 0] = run; run += v0;
  if (base + 1 < M) b[base + 1] = run; run += v1;
  if (base + 2 < M) b[base + 2] = run; run += v2;
  if (base + 3 < M) b[base + 3] = run;
}

__global__ __launch_bounds__(256) void scan3(int* __restrict__ out,
    const int* __restrict__ bsums, int M) {
  int add = bsums[blockIdx.x];
  int idx = blockIdx.x * 1024 + threadIdx.x;
#pragma unroll
  for (int k = 0; k < 4; ++k) {
    int i = idx + k * 256;
    if (i < M) out[i] += add;
  }
}

// ---- fill CSR col array; row_ptr doubles as cursor ----
__global__ __launch_bounds__(256) void fillk(const int* __restrict__ ntime,
    const int* __restrict__ eidx, int* __restrict__ row_ptr, int* __restrict__ col,
    const int* __restrict__ minp, const int* __restrict__ up, int N, int E) {
  int e = blockIdx.x * 256 + threadIdx.x;
  if (e >= E) return;
  int s = eidx[e], d = eidx[E + e];
  int ts = ntime[s], td = ntime[d];
  int m = ts > td ? ts : td;
  int p = (m - minp[0]) / up[0];
  int pos = atomicAdd(&row_ptr[p * N + d], 1);
  col[pos] = s;
}

// ---- weights: transpose + bf16, fragment-linear layout ----
// wt[l][q][n][j]: q in [0,32) = 16B k-block over K=256, n = output col,
// content k = q*8+j; k<128 from w_root[l][k][n], else w_nbr[l][k-128][n].
__global__ __launch_bounds__(256) void wprep(const float* __restrict__ wroot,
    const float* __restrict__ wnbr, unsigned short* __restrict__ wt, int total) {
  int t = blockIdx.x * 256 + threadIdx.x;
  if (t >= total) return;
  int l = t >> 12;
  int rem = t & 4095;
  int q = rem >> 7;
  int n = rem & 127;
  const float* w0 = wroot + l * CD * CD;
  const float* w1 = wnbr + l * CD * CD;
  unsigned short o[8];
#pragma unroll
  for (int j = 0; j < 8; ++j) {
    int k = q * 8 + j;
    float v = (k < CD) ? w0[k * CD + n] : w1[(k - CD) * CD + n];
    o[j] = f2bf(v);
  }
  uint4 pk;
  pk.x = (unsigned)o[0] | ((unsigned)o[1] << 16);
  pk.y = (unsigned)o[2] | ((unsigned)o[3] << 16);
  pk.z = (unsigned)o[4] | ((unsigned)o[5] << 16);
  pk.w = (unsigned)o[6] | ((unsigned)o[7] << 16);
  *(uint4*)(wt + (size_t)l * 32768 + ((size_t)q * CD + n) * 8) = pk;
}

// ---- x_bf init (+ fp32 mirror of seed rows for the head) ----
__global__ __launch_bounds__(256) void xprep(const float* __restrict__ x,
    float* __restrict__ x32, unsigned short* __restrict__ xb, int nseed, int total4) {
  int t = blockIdx.x * 256 + threadIdx.x;
  if (t >= total4) return;
  size_t i = (size_t)t * 4;
  float4 v = *(const float4*)(x + i);
  uint2 pk;
  pk.x = (unsigned)f2bf(v.x) | ((unsigned)f2bf(v.y) << 16);
  pk.y = (unsigned)f2bf(v.z) | ((unsigned)f2bf(v.w) << 16);
  *(uint2*)(xb + i) = pk;
  if ((int)(i >> 7) < nseed) *(float4*)(x32 + i) = v;
}

// ---- pull aggregation over compact involved list ----
// 16-lane group per compact index gi (dst node = nlp[gi]); agg stored at gi.
__global__ __launch_bounds__(256) void aggk(const unsigned short* __restrict__ hbf,
    unsigned short* __restrict__ aggbf, const int* __restrict__ row_ptr,
    const int* __restrict__ deg_pd, const int* __restrict__ col,
    const int* __restrict__ nlp, const int* __restrict__ pcnt, int p, int N) {
  int cnt = pcnt[0];
  int gi = blockIdx.x * 16 + (threadIdx.x >> 4);
  if (gi >= cnt) return;
  int d = nlp[gi];
  int lane = threadIdx.x & 15;
  int key = p * N + d;
  int dg = deg_pd[key];
  uint4 outv = make_uint4(0u, 0u, 0u, 0u);
  if (dg > 0) {
    int start = row_ptr[key] - dg;
    float a[8];
#pragma unroll
    for (int i = 0; i < 8; ++i) a[i] = 0.f;
    for (int j = 0; j < dg; ++j) {
      int s = col[start + j];
      uint4 r = *(const uint4*)(hbf + (size_t)s * CD + lane * 8);
      a[0] += bf2f(r.x & 0xffffu); a[1] += bf2f(r.x >> 16);
      a[2] += bf2f(r.y & 0xffffu); a[3] += bf2f(r.y >> 16);
      a[4] += bf2f(r.z & 0xffffu); a[5] += bf2f(r.z >> 16);
      a[6] += bf2f(r.w & 0xffffu); a[7] += bf2f(r.w >> 16);
    }
    float sc = 1.0f / (float)dg;
    outv.x = (unsigned)f2bf(a[0] * sc) | ((unsigned)f2bf(a[1] * sc) << 16);
    outv.y = (unsigned)f2bf(a[2] * sc) | ((unsigned)f2bf(a[3] * sc) << 16);
    outv.z = (unsigned)f2bf(a[4] * sc) | ((unsigned)f2bf(a[5] * sc) << 16);
    outv.w = (unsigned)f2bf(a[6] * sc) | ((unsigned)f2bf(a[7] * sc) << 16);
  }
  *(uint4*)(aggbf + (size_t)gi * CD + lane * 8) = outv;
}

// ---- MFMA GEMM + bias + LN (+relu -> h_bf | +residual -> x_bf [& x32 seeds]) ----
// Rows = compact involved list. B (128 cols x K=256 bf16 = 64 KB) staged in
// LDS once per block; K-loop is barrier-free. All 16 A fragments (wave-
// private 16B global loads) prefetched before the MFMA loop.
__global__ __launch_bounds__(256, 2) void gemm_mfma(
    const unsigned short* __restrict__ A1, const unsigned short* __restrict__ A2,
    const unsigned short* __restrict__ wt,
    const float* __restrict__ bias, const float* __restrict__ lng,
    const float* __restrict__ lnb,
    unsigned short* __restrict__ hout,
    float* __restrict__ x32, unsigned short* __restrict__ xbf,
    const int* __restrict__ nlp, const int* __restrict__ pcnt,
    int mode, int nseed) {
  int cnt = pcnt[0];
  int rbase = blockIdx.x * 128;
  if (rbase >= cnt) return;

  __shared__ unsigned short Blds[32768];   // 64 KB: whole layer weight panel
  {
    const uint4* src = (const uint4*)wt;
    uint4* dst = (uint4*)Blds;
#pragma unroll
    for (int i = 0; i < 16; ++i) dst[threadIdx.x + i * 256] = src[threadIdx.x + i * 256];
  }
  __syncthreads();

  int tid = threadIdx.x;
  int w = tid >> 6;
  int lane = tid & 63;
  int l15 = lane & 15;
  int quad = lane >> 4;

  // per-lane A rows via compact list (clamped; dup work discarded in epilogue)
  int idxA[2], nodeA[2];
#pragma unroll
  for (int rt = 0; rt < 2; ++rt) {
    int ii = rbase + w * 32 + rt * 16 + l15;
    ii = ii < cnt ? ii : cnt - 1;
    idxA[rt] = ii;
    nodeA[rt] = nlp[ii];
  }

  // prefetch ALL A fragments (16 x 16B = 64 VGPRs) up front
  s16x8 af[4][2][2];
#pragma unroll
  for (int kc = 0; kc < 4; ++kc) {
    int koff = (kc & 1) * 64;
#pragma unroll
    for (int ks = 0; ks < 2; ++ks) {
      int kb = (ks * 4 + quad) * 8;
#pragma unroll
      for (int rt = 0; rt < 2; ++rt) {
        const unsigned short* b = (kc < 2)
            ? A1 + (size_t)nodeA[rt] * CD
            : A2 + (size_t)idxA[rt] * CD;
        af[kc][ks][rt] = *(const s16x8*)(b + koff + kb);
      }
    }
  }

  f32x4 acc[2][8];
#pragma unroll
  for (int rt = 0; rt < 2; ++rt)
#pragma unroll
    for (int ct = 0; ct < 8; ++ct) acc[rt][ct] = (f32x4)(0.f);

#pragma unroll
  for (int kc = 0; kc < 4; ++kc) {
#pragma unroll
    for (int ks = 0; ks < 2; ++ks) {
      int q = kc * 8 + ks * 4 + quad;        // global 16B k-block in [0,32)
      s16x8 bfr[8];
#pragma unroll
      for (int ct = 0; ct < 8; ++ct)
        bfr[ct] = *(const s16x8*)&Blds[((size_t)q * CD + l15) * 8 + (size_t)ct * 128];
#pragma unroll
      for (int rt = 0; rt < 2; ++rt)
#pragma unroll
        for (int ct = 0; ct < 8; ++ct)
          acc[rt][ct] = __builtin_amdgcn_mfma_f32_16x16x32_bf16(
              af[kc][ks][rt], bfr[ct], acc[rt][ct], 0, 0, 0);
    }
  }

  // epilogue: bias + LayerNorm across the 16-lane row group
  float bb[8], gg[8], eb[8];
#pragma unroll
  for (int ct = 0; ct < 8; ++ct) {
    int c = ct * 16 + l15;
    bb[ct] = bias[c]; gg[ct] = lng[c]; eb[ct] = lnb[c];
  }
#pragma unroll
  for (int rt = 0; rt < 2; ++rt) {
#pragma unroll
    for (int reg = 0; reg < 4; ++reg) {
      int ridx = rbase + w * 32 + rt * 16 + quad * 4 + reg;
      float vals[8];
      float s = 0.f, ss = 0.f;
#pragma unroll
      for (int ct = 0; ct < 8; ++ct) {
        float v = acc[rt][ct][reg] + bb[ct];
        vals[ct] = v;
        s += v; ss += v * v;
      }
#pragma unroll
      for (int m = 1; m <= 8; m <<= 1) {
        s  += __shfl_xor(s, m, 64);
        ss += __shfl_xor(ss, m, 64);
      }
      float mu  = s * (1.0f / CD);
      float var = ss * (1.0f / CD) - mu * mu;
      float rs  = rsqrtf(var + 1e-5f);
      if (ridx < cnt) {
        int node = nlp[ridx];
        if (mode == 0) {
#pragma unroll
          for (int ct = 0; ct < 8; ++ct) {
            float o = (vals[ct] - mu) * rs * gg[ct] + eb[ct];
            o = fmaxf(o, 0.f);
            hout[(size_t)node * CD + ct * 16 + l15] = f2bf(o);
          }
        } else {
          bool seed = node < nseed;
#pragma unroll
          for (int ct = 0; ct < 8; ++ct) {
            float o = (vals[ct] - mu) * rs * gg[ct] + eb[ct];
            size_t idx = (size_t)node * CD + ct * 16 + l15;
            float xn = bf2f(xbf[idx]) + o;
            xbf[idx] = f2bf(xn);
            if (seed) x32[idx] += o;
          }
        }
      }
    }
  }
}

// ---- head (reads fp32 seed mirror) ----
__global__ __launch_bounds__(256) void headk(const float* __restrict__ x,
    const float* __restrict__ hw, const float* __restrict__ hb,
    float* __restrict__ out, int seeds) {
  int wave = threadIdx.x >> 6;
  int lane = threadIdx.x & 63;
  int row = blockIdx.x * 4 + wave;
  if (row >= seeds) return;
  const float* xp = x + (size_t)row * CD;
  float v = xp[lane] * hw[lane] + xp[64 + lane] * hw[64 + lane];
#pragma unroll
  for (int m = 1; m < 64; m <<= 1) v += __shfl_xor(v, m, 64);
  if (lane == 0) out[row] = v + hb[0];
}

extern "C" void kernel_launch(void* const* d_in, const int* in_sizes, int n_in,
                              void* d_out, int out_size, void* d_ws, size_t ws_size,
                              hipStream_t stream) {
  const float* x     = (const float*)d_in[0];
  const int*   ntime = (const int*)d_in[1];
  const int*   eidx  = (const int*)d_in[2];
  const float* wroot = (const float*)d_in[3];
  const float* wnbr  = (const float*)d_in[4];
  const float* bias  = (const float*)d_in[5];
  const float* lng   = (const float*)d_in[6];
  const float* lnb   = (const float*)d_in[7];
  const float* headw = (const float*)d_in[8];
  const float* headb = (const float*)d_in[9];
  const int*   minp  = (const int*)d_in[10];
  const int*   up    = (const int*)d_in[12];

  int N = in_sizes[0] / CD;
  int E = in_sizes[2] / 2;
  const int P = 4;
  int M = P * N;
  int nseed = out_size;   // OUT=1 per reference

  size_t off = 0;
  auto alloc = [&](size_t bytes) {
    void* p = (char*)d_ws + off;
    off += (bytes + 255) & ~(size_t)255;
    return p;
  };
  unsigned short* x_bf   = (unsigned short*)alloc((size_t)N * CD * 2);
  unsigned short* h_bf   = (unsigned short*)alloc((size_t)N * CD * 2);
  unsigned short* agg_bf = (unsigned short*)alloc((size_t)N * CD * 2);
  float*          x32    = (float*)alloc((size_t)nseed * CD * 4);
  unsigned short* wt     = (unsigned short*)alloc(2 * 32768 * 2);
  int* deg_pd   = (int*)alloc((size_t)M * 4);
  int* row_ptr  = (int*)alloc((size_t)M * 4);
  int* col      = (int*)alloc((size_t)E * 4);
  int* involved = (int*)alloc((size_t)N * 4);
  int* nlist    = (int*)alloc((size_t)M * 4);
  int* ncnt     = (int*)alloc(256);
  int* bsums    = (int*)alloc(4096);
  (void)ws_size;

  hipMemsetAsync(deg_pd, 0, (size_t)M * 4, stream);
  hipMemsetAsync(involved, 0, (size_t)N * 4, stream);
  hipMemsetAsync(ncnt, 0, 16, stream);

  int egrid = (E + 255) / 256;
  int NB = (M + 1023) / 1024;
  int ggrid = (N + 127) / 128;
  int agrid = (N + 15) / 16;

  xprep<<<(N * 32 + 255) / 256, 256, 0, stream>>>(x, x32, x_bf, nseed, N * 32);
  wprep<<<(8192 + 255) / 256, 256, 0, stream>>>(wroot, wnbr, wt, 8192);
  histk<<<egrid, 256, 0, stream>>>(ntime, eidx, deg_pd, involved, minp, up, N, E);
  compk<<<(N + 255) / 256, 256, 0, stream>>>(involved, nlist, ncnt, N);
  scan1<<<NB, 256, 0, stream>>>(deg_pd, row_ptr, bsums, M);
  scan2<<<1, 256, 0, stream>>>(bsums, NB);
  scan3<<<NB, 256, 0, stream>>>(row_ptr, bsums, M);
  fillk<<<egrid, 256, 0, stream>>>(ntime, eidx, row_ptr, col, minp, up, N, E);

  for (int p = 0; p < P; ++p) {
    const int* nlp = nlist + (size_t)p * N;
    const int* pc  = ncnt + p;
    aggk<<<agrid, 256, 0, stream>>>(x_bf, agg_bf, row_ptr, deg_pd, col, nlp, pc, p, N);
    gemm_mfma<<<ggrid, 256, 0, stream>>>(x_bf, agg_bf, wt,
        bias, lng, lnb, h_bf, nullptr, nullptr, nlp, pc, 0, nseed);
    aggk<<<agrid, 256, 0, stream>>>(h_bf, agg_bf, row_ptr, deg_pd, col, nlp, pc, p, N);
    gemm_mfma<<<ggrid, 256, 0, stream>>>(h_bf, agg_bf, wt + 32768,
        bias + CD, lng + CD, lnb + CD, nullptr, x32, x_bf, nlp, pc, 1, nseed);
  }
  headk<<<(nseed + 3) / 4, 256, 0, stream>>>(x32, headw, headb, (float*)d_out, nseed);
}

// Round 3
// 787.553 us; speedup vs baseline: 1.1749x; 1.1749x over previous
//
#include <hip/hip_runtime.h>

// Temporal GraphSAGE, P=4 periods, C=128, L=2 (reference constants).
// R8: scan-based compaction, ZERO contended atomics. R6/R7 post-mortem:
// compk was invariant at 145 us whether 560K per-thread or 12.5K per-wave
// atomics hit ncnt[4] -> cost was contended-LINE ownership transfers at the
// device coherence point (~12.5K x ~11ns), not atomic count. Now: per-block
// ballot counts -> exclusive scan -> deterministic scatter. nlist comes out
// sorted by node id (better gather locality downstream).
// gemm: LDS-staged weight panel + full A-fragment prefetch (unchanged).

#define CD 128

typedef __attribute__((ext_vector_type(8))) short s16x8;
typedef __attribute__((ext_vector_type(4))) float f32x4;

static __device__ __forceinline__ unsigned short f2bf(float f) {
  unsigned u = __float_as_uint(f);
  u += 0x7FFF + ((u >> 16) & 1);   // round-to-nearest-even
  return (unsigned short)(u >> 16);
}
static __device__ __forceinline__ float bf2f(unsigned us) {
  return __uint_as_float(us << 16);
}

// ---- histogram: per-(period,dst) degree + involved bitmask ----
__global__ __launch_bounds__(256) void histk(const int* __restrict__ ntime,
    const int* __restrict__ eidx, int* __restrict__ deg_pd, int* __restrict__ involved,
    const int* __restrict__ minp, const int* __restrict__ up, int N, int E) {
  int e = blockIdx.x * 256 + threadIdx.x;
  if (e >= E) return;
  int s = eidx[e], d = eidx[E + e];
  int ts = ntime[s], td = ntime[d];
  int m = ts > td ? ts : td;
  int p = (m - minp[0]) / up[0];
  atomicAdd(&deg_pd[p * N + d], 1);
  atomicOr(&involved[s], 1 << p);
  atomicOr(&involved[d], 1 << p);
}

// ---- compaction pass 1: per-block per-period involved counts ----
__global__ __launch_bounds__(256) void compcnt(const int* __restrict__ involved,
    int* __restrict__ bcnt, int NB2, int N) {
  int i = blockIdx.x * 256 + threadIdx.x;
  int bits = (i < N) ? involved[i] : 0;
  int wv = threadIdx.x >> 6;
  int lane = threadIdx.x & 63;
  __shared__ int wcnt[4][4];   // [period][wave]
#pragma unroll
  for (int p = 0; p < 4; ++p) {
    unsigned long long m = __ballot((bits >> p) & 1);
    if (lane == 0) wcnt[p][wv] = __popcll(m);
  }
  __syncthreads();
  if (threadIdx.x < 4) {
    int p = threadIdx.x;
    bcnt[p * NB2 + blockIdx.x] = wcnt[p][0] + wcnt[p][1] + wcnt[p][2] + wcnt[p][3];
  }
}

// ---- compaction pass 2 helper: per-period totals from scan ends ----
__global__ void ncntk(const int* __restrict__ bcnt, const int* __restrict__ bexc,
                      int* __restrict__ ncnt, int NB2) {
  int p = threadIdx.x;
  if (p < 4)
    ncnt[p] = bexc[p * NB2 + NB2 - 1] + bcnt[p * NB2 + NB2 - 1] - bexc[p * NB2];
}

// ---- compaction pass 3: deterministic scatter (sorted by node id) ----
__global__ __launch_bounds__(256) void compscat(const int* __restrict__ involved,
    const int* __restrict__ bexc, int* __restrict__ nlist, int NB2, int N) {
  int i = blockIdx.x * 256 + threadIdx.x;
  int bits = (i < N) ? involved[i] : 0;
  int wv = threadIdx.x >> 6;
  int lane = threadIdx.x & 63;
  unsigned long long lanes_below = (lane == 0) ? 0ull : ((~0ull) >> (64 - lane));
  __shared__ int wcnt[4][4];
  unsigned long long mm[4];
#pragma unroll
  for (int p = 0; p < 4; ++p) {
    mm[p] = __ballot((bits >> p) & 1);
    if (lane == 0) wcnt[p][wv] = __popcll(mm[p]);
  }
  __syncthreads();
#pragma unroll
  for (int p = 0; p < 4; ++p) {
    if (!((bits >> p) & 1)) continue;
    int wpre = (wv > 0 ? wcnt[p][0] : 0) + (wv > 1 ? wcnt[p][1] : 0)
             + (wv > 2 ? wcnt[p][2] : 0);
    int base = bexc[p * NB2 + blockIdx.x] - bexc[p * NB2];
    nlist[p * N + base + wpre + __popcll(mm[p] & lanes_below)] = i;
  }
}

// ---- exclusive scan (3-phase) ----
__global__ __launch_bounds__(256) void scan1(const int* __restrict__ in,
    int* __restrict__ out, int* __restrict__ bsums, int M) {
  __shared__ int lds[256];
  int tid = threadIdx.x;
  int base = blockIdx.x * 1024 + tid * 4;
  int v0 = base + 0 < M ? in[base + 0] : 0;
  int v1 = base + 1 < M ? in[base + 1] : 0;
  int v2 = base + 2 < M ? in[base + 2] : 0;
  int v3 = base + 3 < M ? in[base + 3] : 0;
  int s = v0 + v1 + v2 + v3;
  lds[tid] = s;
  __syncthreads();
  for (int off = 1; off < 256; off <<= 1) {
    int t = tid >= off ? lds[tid - off] : 0;
    __syncthreads();
    lds[tid] += t;
    __syncthreads();
  }
  int run = lds[tid] - s;
  if (base + 0 < M) out[base + 0] = run; run += v0;
  if (base + 1 < M) out[base + 1] = run; run += v1;
  if (base + 2 < M) out[base + 2] = run; run += v2;
  if (base + 3 < M) out[base + 3] = run;
  if (tid == 255) bsums[blockIdx.x] = lds[255];
}

__global__ __launch_bounds__(256) void scan2(int* __restrict__ b, int M) {
  __shared__ int lds[256];
  int tid = threadIdx.x;
  int base = tid * 4;
  int v0 = base + 0 < M ? b[base + 0] : 0;
  int v1 = base + 1 < M ? b[base + 1] : 0;
  int v2 = base + 2 < M ? b[base + 2] : 0;
  int v3 = base + 3 < M ? b[base + 3] : 0;
  int s = v0 + v1 + v2 + v3;
  lds[tid] = s;
  __syncthreads();
  for (int off = 1; off < 256; off <<= 1) {
    int t = tid >= off ? lds[tid - off] : 0;
    __syncthreads();
    lds[tid] += t;
    __syncthreads();
  }
  int run = lds[tid] - s;
  if (base + 0 < M) b[base + 0] = run; run += v0;
  if (base + 1 < M) b[base + 1] = run; run += v1;
  if (base + 2 < M) b[base + 2] = run; run += v2;
  if (base + 3 < M) b[base + 3] = run;
}

__global__ __launch_bounds__(256) void scan3(int* __restrict__ out,
    const int* __restrict__ bsums, int M) {
  int add = bsums[blockIdx.x];
  int idx = blockIdx.x * 1024 + threadIdx.x;
#pragma unroll
  for (int k = 0; k < 4; ++k) {
    int i = idx + k * 256;
    if (i < M) out[i] += add;
  }
}

// ---- fill CSR col array; row_ptr doubles as cursor ----
__global__ __launch_bounds__(256) void fillk(const int* __restrict__ ntime,
    const int* __restrict__ eidx, int* __restrict__ row_ptr, int* __restrict__ col,
    const int* __restrict__ minp, const int* __restrict__ up, int N, int E) {
  int e = blockIdx.x * 256 + threadIdx.x;
  if (e >= E) return;
  int s = eidx[e], d = eidx[E + e];
  int ts = ntime[s], td = ntime[d];
  int m = ts > td ? ts : td;
  int p = (m - minp[0]) / up[0];
  int pos = atomicAdd(&row_ptr[p * N + d], 1);
  col[pos] = s;
}

// ---- weights: transpose + bf16, fragment-linear layout ----
// wt[l][q][n][j]: q in [0,32) = 16B k-block over K=256, n = output col,
// content k = q*8+j; k<128 from w_root[l][k][n], else w_nbr[l][k-128][n].
__global__ __launch_bounds__(256) void wprep(const float* __restrict__ wroot,
    const float* __restrict__ wnbr, unsigned short* __restrict__ wt, int total) {
  int t = blockIdx.x * 256 + threadIdx.x;
  if (t >= total) return;
  int l = t >> 12;
  int rem = t & 4095;
  int q = rem >> 7;
  int n = rem & 127;
  const float* w0 = wroot + l * CD * CD;
  const float* w1 = wnbr + l * CD * CD;
  unsigned short o[8];
#pragma unroll
  for (int j = 0; j < 8; ++j) {
    int k = q * 8 + j;
    float v = (k < CD) ? w0[k * CD + n] : w1[(k - CD) * CD + n];
    o[j] = f2bf(v);
  }
  uint4 pk;
  pk.x = (unsigned)o[0] | ((unsigned)o[1] << 16);
  pk.y = (unsigned)o[2] | ((unsigned)o[3] << 16);
  pk.z = (unsigned)o[4] | ((unsigned)o[5] << 16);
  pk.w = (unsigned)o[6] | ((unsigned)o[7] << 16);
  *(uint4*)(wt + (size_t)l * 32768 + ((size_t)q * CD + n) * 8) = pk;
}

// ---- x_bf init (+ fp32 mirror of seed rows for the head) ----
__global__ __launch_bounds__(256) void xprep(const float* __restrict__ x,
    float* __restrict__ x32, unsigned short* __restrict__ xb, int nseed, int total4) {
  int t = blockIdx.x * 256 + threadIdx.x;
  if (t >= total4) return;
  size_t i = (size_t)t * 4;
  float4 v = *(const float4*)(x + i);
  uint2 pk;
  pk.x = (unsigned)f2bf(v.x) | ((unsigned)f2bf(v.y) << 16);
  pk.y = (unsigned)f2bf(v.z) | ((unsigned)f2bf(v.w) << 16);
  *(uint2*)(xb + i) = pk;
  if ((int)(i >> 7) < nseed) *(float4*)(x32 + i) = v;
}

// ---- pull aggregation over compact involved list ----
// 16-lane group per compact index gi (dst node = nlp[gi]); agg stored at gi.
__global__ __launch_bounds__(256) void aggk(const unsigned short* __restrict__ hbf,
    unsigned short* __restrict__ aggbf, const int* __restrict__ row_ptr,
    const int* __restrict__ deg_pd, const int* __restrict__ col,
    const int* __restrict__ nlp, const int* __restrict__ pcnt, int p, int N) {
  int cnt = pcnt[0];
  int gi = blockIdx.x * 16 + (threadIdx.x >> 4);
  if (gi >= cnt) return;
  int d = nlp[gi];
  int lane = threadIdx.x & 15;
  int key = p * N + d;
  int dg = deg_pd[key];
  uint4 outv = make_uint4(0u, 0u, 0u, 0u);
  if (dg > 0) {
    int start = row_ptr[key] - dg;
    float a[8];
#pragma unroll
    for (int i = 0; i < 8; ++i) a[i] = 0.f;
    for (int j = 0; j < dg; ++j) {
      int s = col[start + j];
      uint4 r = *(const uint4*)(hbf + (size_t)s * CD + lane * 8);
      a[0] += bf2f(r.x & 0xffffu); a[1] += bf2f(r.x >> 16);
      a[2] += bf2f(r.y & 0xffffu); a[3] += bf2f(r.y >> 16);
      a[4] += bf2f(r.z & 0xffffu); a[5] += bf2f(r.z >> 16);
      a[6] += bf2f(r.w & 0xffffu); a[7] += bf2f(r.w >> 16);
    }
    float sc = 1.0f / (float)dg;
    outv.x = (unsigned)f2bf(a[0] * sc) | ((unsigned)f2bf(a[1] * sc) << 16);
    outv.y = (unsigned)f2bf(a[2] * sc) | ((unsigned)f2bf(a[3] * sc) << 16);
    outv.z = (unsigned)f2bf(a[4] * sc) | ((unsigned)f2bf(a[5] * sc) << 16);
    outv.w = (unsigned)f2bf(a[6] * sc) | ((unsigned)f2bf(a[7] * sc) << 16);
  }
  *(uint4*)(aggbf + (size_t)gi * CD + lane * 8) = outv;
}

// ---- MFMA GEMM + bias + LN (+relu -> h_bf | +residual -> x_bf [& x32 seeds]) ----
// Rows = compact involved list. B (128 cols x K=256 bf16 = 64 KB) staged in
// LDS once per block; K-loop is barrier-free. All 16 A fragments (wave-
// private 16B global loads) prefetched before the MFMA loop.
__global__ __launch_bounds__(256, 2) void gemm_mfma(
    const unsigned short* __restrict__ A1, const unsigned short* __restrict__ A2,
    const unsigned short* __restrict__ wt,
    const float* __restrict__ bias, const float* __restrict__ lng,
    const float* __restrict__ lnb,
    unsigned short* __restrict__ hout,
    float* __restrict__ x32, unsigned short* __restrict__ xbf,
    const int* __restrict__ nlp, const int* __restrict__ pcnt,
    int mode, int nseed) {
  int cnt = pcnt[0];
  int rbase = blockIdx.x * 128;
  if (rbase >= cnt) return;

  __shared__ unsigned short Blds[32768];   // 64 KB: whole layer weight panel
  {
    const uint4* src = (const uint4*)wt;
    uint4* dst = (uint4*)Blds;
#pragma unroll
    for (int i = 0; i < 16; ++i) dst[threadIdx.x + i * 256] = src[threadIdx.x + i * 256];
  }
  __syncthreads();

  int tid = threadIdx.x;
  int w = tid >> 6;
  int lane = tid & 63;
  int l15 = lane & 15;
  int quad = lane >> 4;

  // per-lane A rows via compact list (clamped; dup work discarded in epilogue)
  int idxA[2], nodeA[2];
#pragma unroll
  for (int rt = 0; rt < 2; ++rt) {
    int ii = rbase + w * 32 + rt * 16 + l15;
    ii = ii < cnt ? ii : cnt - 1;
    idxA[rt] = ii;
    nodeA[rt] = nlp[ii];
  }

  // prefetch ALL A fragments (16 x 16B = 64 VGPRs) up front
  s16x8 af[4][2][2];
#pragma unroll
  for (int kc = 0; kc < 4; ++kc) {
    int koff = (kc & 1) * 64;
#pragma unroll
    for (int ks = 0; ks < 2; ++ks) {
      int kb = (ks * 4 + quad) * 8;
#pragma unroll
      for (int rt = 0; rt < 2; ++rt) {
        const unsigned short* b = (kc < 2)
            ? A1 + (size_t)nodeA[rt] * CD
            : A2 + (size_t)idxA[rt] * CD;
        af[kc][ks][rt] = *(const s16x8*)(b + koff + kb);
      }
    }
  }

  f32x4 acc[2][8];
#pragma unroll
  for (int rt = 0; rt < 2; ++rt)
#pragma unroll
    for (int ct = 0; ct < 8; ++ct) acc[rt][ct] = (f32x4)(0.f);

#pragma unroll
  for (int kc = 0; kc < 4; ++kc) {
#pragma unroll
    for (int ks = 0; ks < 2; ++ks) {
      int q = kc * 8 + ks * 4 + quad;        // global 16B k-block in [0,32)
      s16x8 bfr[8];
#pragma unroll
      for (int ct = 0; ct < 8; ++ct)
        bfr[ct] = *(const s16x8*)&Blds[((size_t)q * CD + l15) * 8 + (size_t)ct * 128];
#pragma unroll
      for (int rt = 0; rt < 2; ++rt)
#pragma unroll
        for (int ct = 0; ct < 8; ++ct)
          acc[rt][ct] = __builtin_amdgcn_mfma_f32_16x16x32_bf16(
              af[kc][ks][rt], bfr[ct], acc[rt][ct], 0, 0, 0);
    }
  }

  // epilogue: bias + LayerNorm across the 16-lane row group
  float bb[8], gg[8], eb[8];
#pragma unroll
  for (int ct = 0; ct < 8; ++ct) {
    int c = ct * 16 + l15;
    bb[ct] = bias[c]; gg[ct] = lng[c]; eb[ct] = lnb[c];
  }
#pragma unroll
  for (int rt = 0; rt < 2; ++rt) {
#pragma unroll
    for (int reg = 0; reg < 4; ++reg) {
      int ridx = rbase + w * 32 + rt * 16 + quad * 4 + reg;
      float vals[8];
      float s = 0.f, ss = 0.f;
#pragma unroll
      for (int ct = 0; ct < 8; ++ct) {
        float v = acc[rt][ct][reg] + bb[ct];
        vals[ct] = v;
        s += v; ss += v * v;
      }
#pragma unroll
      for (int m = 1; m <= 8; m <<= 1) {
        s  += __shfl_xor(s, m, 64);
        ss += __shfl_xor(ss, m, 64);
      }
      float mu  = s * (1.0f / CD);
      float var = ss * (1.0f / CD) - mu * mu;
      float rs  = rsqrtf(var + 1e-5f);
      if (ridx < cnt) {
        int node = nlp[ridx];
        if (mode == 0) {
#pragma unroll
          for (int ct = 0; ct < 8; ++ct) {
            float o = (vals[ct] - mu) * rs * gg[ct] + eb[ct];
            o = fmaxf(o, 0.f);
            hout[(size_t)node * CD + ct * 16 + l15] = f2bf(o);
          }
        } else {
          bool seed = node < nseed;
#pragma unroll
          for (int ct = 0; ct < 8; ++ct) {
            float o = (vals[ct] - mu) * rs * gg[ct] + eb[ct];
            size_t idx = (size_t)node * CD + ct * 16 + l15;
            float xn = bf2f(xbf[idx]) + o;
            xbf[idx] = f2bf(xn);
            if (seed) x32[idx] += o;
          }
        }
      }
    }
  }
}

// ---- head (reads fp32 seed mirror) ----
__global__ __launch_bounds__(256) void headk(const float* __restrict__ x,
    const float* __restrict__ hw, const float* __restrict__ hb,
    float* __restrict__ out, int seeds) {
  int wave = threadIdx.x >> 6;
  int lane = threadIdx.x & 63;
  int row = blockIdx.x * 4 + wave;
  if (row >= seeds) return;
  const float* xp = x + (size_t)row * CD;
  float v = xp[lane] * hw[lane] + xp[64 + lane] * hw[64 + lane];
#pragma unroll
  for (int m = 1; m < 64; m <<= 1) v += __shfl_xor(v, m, 64);
  if (lane == 0) out[row] = v + hb[0];
}

extern "C" void kernel_launch(void* const* d_in, const int* in_sizes, int n_in,
                              void* d_out, int out_size, void* d_ws, size_t ws_size,
                              hipStream_t stream) {
  const float* x     = (const float*)d_in[0];
  const int*   ntime = (const int*)d_in[1];
  const int*   eidx  = (const int*)d_in[2];
  const float* wroot = (const float*)d_in[3];
  const float* wnbr  = (const float*)d_in[4];
  const float* bias  = (const float*)d_in[5];
  const float* lng   = (const float*)d_in[6];
  const float* lnb   = (const float*)d_in[7];
  const float* headw = (const float*)d_in[8];
  const float* headb = (const float*)d_in[9];
  const int*   minp  = (const int*)d_in[10];
  const int*   up    = (const int*)d_in[12];

  int N = in_sizes[0] / CD;
  int E = in_sizes[2] / 2;
  const int P = 4;
  int M = P * N;
  int nseed = out_size;   // OUT=1 per reference

  size_t off = 0;
  auto alloc = [&](size_t bytes) {
    void* p = (char*)d_ws + off;
    off += (bytes + 255) & ~(size_t)255;
    return p;
  };
  unsigned short* x_bf   = (unsigned short*)alloc((size_t)N * CD * 2);
  unsigned short* h_bf   = (unsigned short*)alloc((size_t)N * CD * 2);
  unsigned short* agg_bf = (unsigned short*)alloc((size_t)N * CD * 2);
  float*          x32    = (float*)alloc((size_t)nseed * CD * 4);
  unsigned short* wt     = (unsigned short*)alloc(2 * 32768 * 2);
  int* deg_pd   = (int*)alloc((size_t)M * 4);
  int* row_ptr  = (int*)alloc((size_t)M * 4);
  int* col      = (int*)alloc((size_t)E * 4);
  int* involved = (int*)alloc((size_t)N * 4);
  int* nlist    = (int*)alloc((size_t)M * 4);
  int* ncnt     = (int*)alloc(256);
  int* bsums    = (int*)alloc(4096);

  int NB2 = (N + 255) / 256;               // compaction blocks
  int M2 = 4 * NB2;                        // bcnt/bexc length
  int* bcnt = (int*)alloc((size_t)M2 * 4);
  int* bexc = (int*)alloc((size_t)M2 * 4);
  (void)ws_size;

  hipMemsetAsync(deg_pd, 0, (size_t)M * 4, stream);
  hipMemsetAsync(involved, 0, (size_t)N * 4, stream);

  int egrid = (E + 255) / 256;
  int NB = (M + 1023) / 1024;
  int NBc = (M2 + 1023) / 1024;
  int ggrid = (N + 127) / 128;
  int agrid = (N + 15) / 16;

  xprep<<<(N * 32 + 255) / 256, 256, 0, stream>>>(x, x32, x_bf, nseed, N * 32);
  wprep<<<(8192 + 255) / 256, 256, 0, stream>>>(wroot, wnbr, wt, 8192);
  histk<<<egrid, 256, 0, stream>>>(ntime, eidx, deg_pd, involved, minp, up, N, E);

  // compaction: count -> scan -> totals -> scatter (no contended atomics)
  compcnt<<<NB2, 256, 0, stream>>>(involved, bcnt, NB2, N);
  scan1<<<NBc, 256, 0, stream>>>(bcnt, bexc, bsums, M2);
  scan2<<<1, 256, 0, stream>>>(bsums, NBc);
  scan3<<<NBc, 256, 0, stream>>>(bexc, bsums, M2);
  ncntk<<<1, 4, 0, stream>>>(bcnt, bexc, ncnt, NB2);
  compscat<<<NB2, 256, 0, stream>>>(involved, bexc, nlist, NB2, N);

  // CSR build
  scan1<<<NB, 256, 0, stream>>>(deg_pd, row_ptr, bsums, M);
  scan2<<<1, 256, 0, stream>>>(bsums, NB);
  scan3<<<NB, 256, 0, stream>>>(row_ptr, bsums, M);
  fillk<<<egrid, 256, 0, stream>>>(ntime, eidx, row_ptr, col, minp, up, N, E);

  for (int p = 0; p < P; ++p) {
    const int* nlp = nlist + (size_t)p * N;
    const int* pc  = ncnt + p;
    aggk<<<agrid, 256, 0, stream>>>(x_bf, agg_bf, row_ptr, deg_pd, col, nlp, pc, p, N);
    gemm_mfma<<<ggrid, 256, 0, stream>>>(x_bf, agg_bf, wt,
        bias, lng, lnb, h_bf, nullptr, nullptr, nlp, pc, 0, nseed);
    aggk<<<agrid, 256, 0, stream>>>(h_bf, agg_bf, row_ptr, deg_pd, col, nlp, pc, p, N);
    gemm_mfma<<<ggrid, 256, 0, stream>>>(h_bf, agg_bf, wt + 32768,
        bias + CD, lng + CD, lnb + CD, nullptr, x32, x_bf, nlp, pc, 1, nseed);
  }
  headk<<<(nseed + 3) / 4, 256, 0, stream>>>(x32, headw, headb, (float*)d_out, nseed);
}

// Round 4
// 698.330 us; speedup vs baseline: 1.3250x; 1.1278x over previous
//
#include <hip/hip_runtime.h>

// Temporal GraphSAGE, P=4 periods, C=128, L=2 (reference constants).
// R9: (1) PERMUTED CHANNEL LAYOUT pi(c) = (c&15)*8 + (c>>4) for all bf16
// feature rows (x_bf, h, agg) + matching K-row permutation in wt. The MFMA
// C-fragment (8 cols at stride 16 per lane) now lands on 16B-contiguous
// storage -> epilogue is 8 uint4 stores (mode0) / 8 uint4 RMW (mode1)
// instead of 64-128 sub-dword VMEM ops per lane (R8's hidden bottleneck:
// MfmaUtil 5%, 1.4TB/s, epilogue issue/latency flood).
// (2) h stored COMPACT (h_comp[gi]) -> L1-gemm writes and L2-gemm A1 reads
// are sequential streams; L2 aggk maps src->gi via per-period cidx (L2-hot).
// aggk stays elementwise -> permutation-transparent. Bitwise-identical math.

#define CD 128

typedef __attribute__((ext_vector_type(8))) short s16x8;
typedef __attribute__((ext_vector_type(4))) float f32x4;

static __device__ __forceinline__ unsigned short f2bf(float f) {
  unsigned u = __float_as_uint(f);
  u += 0x7FFF + ((u >> 16) & 1);   // round-to-nearest-even
  return (unsigned short)(u >> 16);
}
static __device__ __forceinline__ float bf2f(unsigned us) {
  return __uint_as_float(us << 16);
}

// ---- histogram: per-(period,dst) degree + involved bitmask ----
__global__ __launch_bounds__(256) void histk(const int* __restrict__ ntime,
    const int* __restrict__ eidx, int* __restrict__ deg_pd, int* __restrict__ involved,
    const int* __restrict__ minp, const int* __restrict__ up, int N, int E) {
  int e = blockIdx.x * 256 + threadIdx.x;
  if (e >= E) return;
  int s = eidx[e], d = eidx[E + e];
  int ts = ntime[s], td = ntime[d];
  int m = ts > td ? ts : td;
  int p = (m - minp[0]) / up[0];
  atomicAdd(&deg_pd[p * N + d], 1);
  atomicOr(&involved[s], 1 << p);
  atomicOr(&involved[d], 1 << p);
}

// ---- compaction pass 1: per-block per-period involved counts ----
__global__ __launch_bounds__(256) void compcnt(const int* __restrict__ involved,
    int* __restrict__ bcnt, int NB2, int N) {
  int i = blockIdx.x * 256 + threadIdx.x;
  int bits = (i < N) ? involved[i] : 0;
  int wv = threadIdx.x >> 6;
  int lane = threadIdx.x & 63;
  __shared__ int wcnt[4][4];   // [period][wave]
#pragma unroll
  for (int p = 0; p < 4; ++p) {
    unsigned long long m = __ballot((bits >> p) & 1);
    if (lane == 0) wcnt[p][wv] = __popcll(m);
  }
  __syncthreads();
  if (threadIdx.x < 4) {
    int p = threadIdx.x;
    bcnt[p * NB2 + blockIdx.x] = wcnt[p][0] + wcnt[p][1] + wcnt[p][2] + wcnt[p][3];
  }
}

// ---- compaction pass 2 helper: per-period totals from scan ends ----
__global__ void ncntk(const int* __restrict__ bcnt, const int* __restrict__ bexc,
                      int* __restrict__ ncnt, int NB2) {
  int p = threadIdx.x;
  if (p < 4)
    ncnt[p] = bexc[p * NB2 + NB2 - 1] + bcnt[p * NB2 + NB2 - 1] - bexc[p * NB2];
}

// ---- compaction pass 3: deterministic scatter + inverse map (node->gi) ----
__global__ __launch_bounds__(256) void compscat(const int* __restrict__ involved,
    const int* __restrict__ bexc, int* __restrict__ nlist, int* __restrict__ cidx,
    int NB2, int N) {
  int i = blockIdx.x * 256 + threadIdx.x;
  int bits = (i < N) ? involved[i] : 0;
  int wv = threadIdx.x >> 6;
  int lane = threadIdx.x & 63;
  unsigned long long lanes_below = (lane == 0) ? 0ull : ((~0ull) >> (64 - lane));
  __shared__ int wcnt[4][4];
  unsigned long long mm[4];
#pragma unroll
  for (int p = 0; p < 4; ++p) {
    mm[p] = __ballot((bits >> p) & 1);
    if (lane == 0) wcnt[p][wv] = __popcll(mm[p]);
  }
  __syncthreads();
#pragma unroll
  for (int p = 0; p < 4; ++p) {
    if (!((bits >> p) & 1)) continue;
    int wpre = (wv > 0 ? wcnt[p][0] : 0) + (wv > 1 ? wcnt[p][1] : 0)
             + (wv > 2 ? wcnt[p][2] : 0);
    int base = bexc[p * NB2 + blockIdx.x] - bexc[p * NB2];
    int pos = base + wpre + __popcll(mm[p] & lanes_below);
    nlist[p * N + pos] = i;
    cidx[p * N + i] = pos;
  }
}

// ---- exclusive scan (3-phase) ----
__global__ __launch_bounds__(256) void scan1(const int* __restrict__ in,
    int* __restrict__ out, int* __restrict__ bsums, int M) {
  __shared__ int lds[256];
  int tid = threadIdx.x;
  int base = blockIdx.x * 1024 + tid * 4;
  int v0 = base + 0 < M ? in[base + 0] : 0;
  int v1 = base + 1 < M ? in[base + 1] : 0;
  int v2 = base + 2 < M ? in[base + 2] : 0;
  int v3 = base + 3 < M ? in[base + 3] : 0;
  int s = v0 + v1 + v2 + v3;
  lds[tid] = s;
  __syncthreads();
  for (int off = 1; off < 256; off <<= 1) {
    int t = tid >= off ? lds[tid - off] : 0;
    __syncthreads();
    lds[tid] += t;
    __syncthreads();
  }
  int run = lds[tid] - s;
  if (base + 0 < M) out[base + 0] = run; run += v0;
  if (base + 1 < M) out[base + 1] = run; run += v1;
  if (base + 2 < M) out[base + 2] = run; run += v2;
  if (base + 3 < M) out[base + 3] = run;
  if (tid == 255) bsums[blockIdx.x] = lds[255];
}

__global__ __launch_bounds__(256) void scan2(int* __restrict__ b, int M) {
  __shared__ int lds[256];
  int tid = threadIdx.x;
  int base = tid * 4;
  int v0 = base + 0 < M ? b[base + 0] : 0;
  int v1 = base + 1 < M ? b[base + 1] : 0;
  int v2 = base + 2 < M ? b[base + 2] : 0;
  int v3 = base + 3 < M ? b[base + 3] : 0;
  int s = v0 + v1 + v2 + v3;
  lds[tid] = s;
  __syncthreads();
  for (int off = 1; off < 256; off <<= 1) {
    int t = tid >= off ? lds[tid - off] : 0;
    __syncthreads();
    lds[tid] += t;
    __syncthreads();
  }
  int run = lds[tid] - s;
  if (base + 0 < M) b[base + 0] = run; run += v0;
  if (base + 1 < M) b[base + 1] = run; run += v1;
  if (base + 2 < M) b[base + 2] = run; run += v2;
  if (base + 3 < M) b[base + 3] = run;
}

__global__ __launch_bounds__(256) void scan3(int* __restrict__ out,
    const int* __restrict__ bsums, int M) {
  int add = bsums[blockIdx.x];
  int idx = blockIdx.x * 1024 + threadIdx.x;
#pragma unroll
  for (int k = 0; k < 4; ++k) {
    int i = idx + k * 256;
    if (i < M) out[i] += add;
  }
}

// ---- fill CSR col array; row_ptr doubles as cursor ----
__global__ __launch_bounds__(256) void fillk(const int* __restrict__ ntime,
    const int* __restrict__ eidx, int* __restrict__ row_ptr, int* __restrict__ col,
    const int* __restrict__ minp, const int* __restrict__ up, int N, int E) {
  int e = blockIdx.x * 256 + threadIdx.x;
  if (e >= E) return;
  int s = eidx[e], d = eidx[E + e];
  int ts = ntime[s], td = ntime[d];
  int m = ts > td ? ts : td;
  int p = (m - minp[0]) / up[0];
  int pos = atomicAdd(&row_ptr[p * N + d], 1);
  col[pos] = s;
}

// ---- weights: bf16, fragment-linear, K-rows PERMUTED to match pi-layout ----
// wt[l][q][n][j]: q in [0,32) = 16B k-block. Stored k-position kp = (q&15)*8+j
// within the half; true k = invpi(kp) = (kp&7)*16 + (kp>>3). q<16 -> w_root,
// q>=16 -> w_nbr.
__global__ __launch_bounds__(256) void wprep(const float* __restrict__ wroot,
    const float* __restrict__ wnbr, unsigned short* __restrict__ wt, int total) {
  int t = blockIdx.x * 256 + threadIdx.x;
  if (t >= total) return;
  int l = t >> 12;
  int rem = t & 4095;
  int q = rem >> 7;
  int n = rem & 127;
  const float* src = (q < 16) ? (wroot + l * CD * CD) : (wnbr + l * CD * CD);
  int qh = q & 15;
  unsigned short o[8];
#pragma unroll
  for (int j = 0; j < 8; ++j) {
    int kp = qh * 8 + j;                 // permuted k within half
    int kt = (kp & 7) * 16 + (kp >> 3);  // true k
    o[j] = f2bf(src[kt * CD + n]);
  }
  uint4 pk;
  pk.x = (unsigned)o[0] | ((unsigned)o[1] << 16);
  pk.y = (unsigned)o[2] | ((unsigned)o[3] << 16);
  pk.z = (unsigned)o[4] | ((unsigned)o[5] << 16);
  pk.w = (unsigned)o[6] | ((unsigned)o[7] << 16);
  *(uint4*)(wt + (size_t)l * 32768 + ((size_t)q * CD + n) * 8) = pk;
}

// ---- x_bf init in permuted layout: position j*8+t holds true col t*16+j ----
__global__ __launch_bounds__(256) void xprep(const float* __restrict__ x,
    unsigned short* __restrict__ xb, int total) {
  int t = blockIdx.x * 256 + threadIdx.x;
  if (t >= total) return;            // total = N*16
  int row = t >> 4, j = t & 15;
  const float* xp = x + (size_t)row * CD + j;
  unsigned short o[8];
#pragma unroll
  for (int tt = 0; tt < 8; ++tt) o[tt] = f2bf(xp[tt * 16]);
  uint4 pk;
  pk.x = (unsigned)o[0] | ((unsigned)o[1] << 16);
  pk.y = (unsigned)o[2] | ((unsigned)o[3] << 16);
  pk.z = (unsigned)o[4] | ((unsigned)o[5] << 16);
  pk.w = (unsigned)o[6] | ((unsigned)o[7] << 16);
  *(uint4*)(xb + (size_t)row * CD + j * 8) = pk;
}

// ---- fp32 mirror of seed rows (original layout) for the head ----
__global__ __launch_bounds__(256) void x32prep(const float* __restrict__ x,
    float* __restrict__ x32, int total4) {
  int t = blockIdx.x * 256 + threadIdx.x;
  if (t >= total4) return;
  *(float4*)(x32 + (size_t)t * 4) = *(const float4*)(x + (size_t)t * 4);
}

// ---- pull aggregation over compact involved list ----
// 16-lane group per compact index gi (dst node = nlp[gi]); agg stored at gi.
// cmap != NULL: source rows are compact-indexed via cmap[s] (layer 2).
__global__ __launch_bounds__(256) void aggk(const unsigned short* __restrict__ hbf,
    unsigned short* __restrict__ aggbf, const int* __restrict__ row_ptr,
    const int* __restrict__ deg_pd, const int* __restrict__ col,
    const int* __restrict__ nlp, const int* __restrict__ pcnt,
    const int* __restrict__ cmap, int p, int N) {
  int cnt = pcnt[0];
  int gi = blockIdx.x * 16 + (threadIdx.x >> 4);
  if (gi >= cnt) return;
  int d = nlp[gi];
  int lane = threadIdx.x & 15;
  int key = p * N + d;
  int dg = deg_pd[key];
  uint4 outv = make_uint4(0u, 0u, 0u, 0u);
  if (dg > 0) {
    int start = row_ptr[key] - dg;
    float a[8];
#pragma unroll
    for (int i = 0; i < 8; ++i) a[i] = 0.f;
    for (int j = 0; j < dg; ++j) {
      int s = col[start + j];
      int r = cmap ? cmap[s] : s;
      uint4 rv = *(const uint4*)(hbf + (size_t)r * CD + lane * 8);
      a[0] += bf2f(rv.x & 0xffffu); a[1] += bf2f(rv.x >> 16);
      a[2] += bf2f(rv.y & 0xffffu); a[3] += bf2f(rv.y >> 16);
      a[4] += bf2f(rv.z & 0xffffu); a[5] += bf2f(rv.z >> 16);
      a[6] += bf2f(rv.w & 0xffffu); a[7] += bf2f(rv.w >> 16);
    }
    float sc = 1.0f / (float)dg;
    outv.x = (unsigned)f2bf(a[0] * sc) | ((unsigned)f2bf(a[1] * sc) << 16);
    outv.y = (unsigned)f2bf(a[2] * sc) | ((unsigned)f2bf(a[3] * sc) << 16);
    outv.z = (unsigned)f2bf(a[4] * sc) | ((unsigned)f2bf(a[5] * sc) << 16);
    outv.w = (unsigned)f2bf(a[6] * sc) | ((unsigned)f2bf(a[7] * sc) << 16);
  }
  *(uint4*)(aggbf + (size_t)gi * CD + lane * 8) = outv;
}

// ---- MFMA GEMM + bias + LN; vectorized epilogue via permuted layout ----
// mode 0 (layer 1): A1 = x_bf[node] gather; out = relu(LN) -> h_comp[gi]
//   (sequential uint4 stores).
// mode 1 (layer 2): A1 = h_comp[gi] stream; residual RMW x_bf[node] as uint4
//   (+ scattered f32 adds into x32 for seed rows).
__global__ __launch_bounds__(256, 2) void gemm_mfma(
    const unsigned short* __restrict__ A1, const unsigned short* __restrict__ A2,
    const unsigned short* __restrict__ wt,
    const float* __restrict__ bias, const float* __restrict__ lng,
    const float* __restrict__ lnb,
    unsigned short* __restrict__ hout,
    float* __restrict__ x32, unsigned short* __restrict__ xbf,
    const int* __restrict__ nlp, const int* __restrict__ pcnt,
    int mode, int nseed) {
  int cnt = pcnt[0];
  int rbase = blockIdx.x * 128;
  if (rbase >= cnt) return;

  __shared__ unsigned short Blds[32768];   // 64 KB: whole layer weight panel
  {
    const uint4* src = (const uint4*)wt;
    uint4* dst = (uint4*)Blds;
#pragma unroll
    for (int i = 0; i < 16; ++i) dst[threadIdx.x + i * 256] = src[threadIdx.x + i * 256];
  }
  __syncthreads();

  int tid = threadIdx.x;
  int w = tid >> 6;
  int lane = tid & 63;
  int l15 = lane & 15;
  int quad = lane >> 4;

  // per-lane A rows (clamped; duplicate work beyond cnt discarded in epilogue)
  const unsigned short* base1[2];
  const unsigned short* base2[2];
#pragma unroll
  for (int rt = 0; rt < 2; ++rt) {
    int ii = rbase + w * 32 + rt * 16 + l15;
    ii = ii < cnt ? ii : cnt - 1;
    int arow = (mode == 0) ? nlp[ii] : ii;   // layer1: node gather; layer2: stream
    base1[rt] = A1 + (size_t)arow * CD;
    base2[rt] = A2 + (size_t)ii * CD;
  }

  // prefetch ALL A fragments (16 x 16B = 64 VGPRs) up front
  s16x8 af[4][2][2];
#pragma unroll
  for (int kc = 0; kc < 4; ++kc) {
    int koff = (kc & 1) * 64;
#pragma unroll
    for (int ks = 0; ks < 2; ++ks) {
      int kb = (ks * 4 + quad) * 8;
#pragma unroll
      for (int rt = 0; rt < 2; ++rt)
        af[kc][ks][rt] = *(const s16x8*)((kc < 2 ? base1[rt] : base2[rt]) + koff + kb);
    }
  }

  f32x4 acc[2][8];
#pragma unroll
  for (int rt = 0; rt < 2; ++rt)
#pragma unroll
    for (int ct = 0; ct < 8; ++ct) acc[rt][ct] = (f32x4)(0.f);

#pragma unroll
  for (int kc = 0; kc < 4; ++kc) {
#pragma unroll
    for (int ks = 0; ks < 2; ++ks) {
      int q = kc * 8 + ks * 4 + quad;        // global 16B k-block in [0,32)
      s16x8 bfr[8];
#pragma unroll
      for (int ct = 0; ct < 8; ++ct)
        bfr[ct] = *(const s16x8*)&Blds[((size_t)q * CD + l15) * 8 + (size_t)ct * 128];
#pragma unroll
      for (int rt = 0; rt < 2; ++rt)
#pragma unroll
        for (int ct = 0; ct < 8; ++ct)
          acc[rt][ct] = __builtin_amdgcn_mfma_f32_16x16x32_bf16(
              af[kc][ks][rt], bfr[ct], acc[rt][ct], 0, 0, 0);
    }
  }

  // epilogue: bias + LayerNorm across the 16-lane row group (true col = ct*16+l15)
  float bb[8], gg[8], eb[8];
#pragma unroll
  for (int ct = 0; ct < 8; ++ct) {
    int c = ct * 16 + l15;
    bb[ct] = bias[c]; gg[ct] = lng[c]; eb[ct] = lnb[c];
  }
#pragma unroll
  for (int rt = 0; rt < 2; ++rt) {
#pragma unroll
    for (int reg = 0; reg < 4; ++reg) {
      int ridx = rbase + w * 32 + rt * 16 + quad * 4 + reg;
      float vals[8];
      float s = 0.f, ss = 0.f;
#pragma unroll
      for (int ct = 0; ct < 8; ++ct) {
        float v = acc[rt][ct][reg] + bb[ct];
        vals[ct] = v;
        s += v; ss += v * v;
      }
#pragma unroll
      for (int m = 1; m <= 8; m <<= 1) {
        s  += __shfl_xor(s, m, 64);
        ss += __shfl_xor(ss, m, 64);
      }
      float mu  = s * (1.0f / CD);
      float var = ss * (1.0f / CD) - mu * mu;
      float rs  = rsqrtf(var + 1e-5f);
      if (ridx < cnt) {
        float o[8];
#pragma unroll
        for (int ct = 0; ct < 8; ++ct) o[ct] = (vals[ct] - mu) * rs * gg[ct] + eb[ct];
        if (mode == 0) {
          uint4 pk;
          pk.x = (unsigned)f2bf(fmaxf(o[0], 0.f)) | ((unsigned)f2bf(fmaxf(o[1], 0.f)) << 16);
          pk.y = (unsigned)f2bf(fmaxf(o[2], 0.f)) | ((unsigned)f2bf(fmaxf(o[3], 0.f)) << 16);
          pk.z = (unsigned)f2bf(fmaxf(o[4], 0.f)) | ((unsigned)f2bf(fmaxf(o[5], 0.f)) << 16);
          pk.w = (unsigned)f2bf(fmaxf(o[6], 0.f)) | ((unsigned)f2bf(fmaxf(o[7], 0.f)) << 16);
          *(uint4*)(hout + (size_t)ridx * CD + l15 * 8) = pk;   // compact, sequential
        } else {
          int node = nlp[ridx];
          unsigned short* xp = xbf + (size_t)node * CD + l15 * 8;
          uint4 old = *(const uint4*)xp;
          float xn0 = bf2f(old.x & 0xffffu) + o[0], xn1 = bf2f(old.x >> 16) + o[1];
          float xn2 = bf2f(old.y & 0xffffu) + o[2], xn3 = bf2f(old.y >> 16) + o[3];
          float xn4 = bf2f(old.z & 0xffffu) + o[4], xn5 = bf2f(old.z >> 16) + o[5];
          float xn6 = bf2f(old.w & 0xffffu) + o[6], xn7 = bf2f(old.w >> 16) + o[7];
          uint4 pk;
          pk.x = (unsigned)f2bf(xn0) | ((unsigned)f2bf(xn1) << 16);
          pk.y = (unsigned)f2bf(xn2) | ((unsigned)f2bf(xn3) << 16);
          pk.z = (unsigned)f2bf(xn4) | ((unsigned)f2bf(xn5) << 16);
          pk.w = (unsigned)f2bf(xn6) | ((unsigned)f2bf(xn7) << 16);
          *(uint4*)xp = pk;
          if (node < nseed) {
            float* x3 = x32 + (size_t)node * CD + l15;
#pragma unroll
            for (int ct = 0; ct < 8; ++ct) x3[ct * 16] += o[ct];
          }
        }
      }
    }
  }
}

// ---- head (reads fp32 seed mirror, original layout) ----
__global__ __launch_bounds__(256) void headk(const float* __restrict__ x,
    const float* __restrict__ hw, const float* __restrict__ hb,
    float* __restrict__ out, int seeds) {
  int wave = threadIdx.x >> 6;
  int lane = threadIdx.x & 63;
  int row = blockIdx.x * 4 + wave;
  if (row >= seeds) return;
  const float* xp = x + (size_t)row * CD;
  float v = xp[lane] * hw[lane] + xp[64 + lane] * hw[64 + lane];
#pragma unroll
  for (int m = 1; m < 64; m <<= 1) v += __shfl_xor(v, m, 64);
  if (lane == 0) out[row] = v + hb[0];
}

extern "C" void kernel_launch(void* const* d_in, const int* in_sizes, int n_in,
                              void* d_out, int out_size, void* d_ws, size_t ws_size,
                              hipStream_t stream) {
  const float* x     = (const float*)d_in[0];
  const int*   ntime = (const int*)d_in[1];
  const int*   eidx  = (const int*)d_in[2];
  const float* wroot = (const float*)d_in[3];
  const float* wnbr  = (const float*)d_in[4];
  const float* bias  = (const float*)d_in[5];
  const float* lng   = (const float*)d_in[6];
  const float* lnb   = (const float*)d_in[7];
  const float* headw = (const float*)d_in[8];
  const float* headb = (const float*)d_in[9];
  const int*   minp  = (const int*)d_in[10];
  const int*   up    = (const int*)d_in[12];

  int N = in_sizes[0] / CD;
  int E = in_sizes[2] / 2;
  const int P = 4;
  int M = P * N;
  int nseed = out_size;   // OUT=1 per reference

  size_t off = 0;
  auto alloc = [&](size_t bytes) {
    void* p = (char*)d_ws + off;
    off += (bytes + 255) & ~(size_t)255;
    return p;
  };
  unsigned short* x_bf   = (unsigned short*)alloc((size_t)N * CD * 2);
  unsigned short* h_bf   = (unsigned short*)alloc((size_t)N * CD * 2);   // compact rows
  unsigned short* agg_bf = (unsigned short*)alloc((size_t)N * CD * 2);   // compact rows
  float*          x32    = (float*)alloc((size_t)nseed * CD * 4);
  unsigned short* wt     = (unsigned short*)alloc(2 * 32768 * 2);
  int* deg_pd   = (int*)alloc((size_t)M * 4);
  int* row_ptr  = (int*)alloc((size_t)M * 4);
  int* col      = (int*)alloc((size_t)E * 4);
  int* involved = (int*)alloc((size_t)N * 4);
  int* nlist    = (int*)alloc((size_t)M * 4);
  int* cidx     = (int*)alloc((size_t)M * 4);
  int* ncnt     = (int*)alloc(256);
  int* bsums    = (int*)alloc(4096);

  int NB2 = (N + 255) / 256;               // compaction blocks
  int M2 = 4 * NB2;                        // bcnt/bexc length
  int* bcnt = (int*)alloc((size_t)M2 * 4);
  int* bexc = (int*)alloc((size_t)M2 * 4);
  (void)ws_size;

  hipMemsetAsync(deg_pd, 0, (size_t)M * 4, stream);
  hipMemsetAsync(involved, 0, (size_t)N * 4, stream);

  int egrid = (E + 255) / 256;
  int NB = (M + 1023) / 1024;
  int NBc = (M2 + 1023) / 1024;
  int ggrid = (N + 127) / 128;
  int agrid = (N + 15) / 16;

  xprep<<<(N * 16 + 255) / 256, 256, 0, stream>>>(x, x_bf, N * 16);
  x32prep<<<(nseed * 32 + 255) / 256, 256, 0, stream>>>(x, x32, nseed * 32);
  wprep<<<(8192 + 255) / 256, 256, 0, stream>>>(wroot, wnbr, wt, 8192);
  histk<<<egrid, 256, 0, stream>>>(ntime, eidx, deg_pd, involved, minp, up, N, E);

  // compaction: count -> scan -> totals -> scatter (+ node->gi map)
  compcnt<<<NB2, 256, 0, stream>>>(involved, bcnt, NB2, N);
  scan1<<<NBc, 256, 0, stream>>>(bcnt, bexc, bsums, M2);
  scan2<<<1, 256, 0, stream>>>(bsums, NBc);
  scan3<<<NBc, 256, 0, stream>>>(bexc, bsums, M2);
  ncntk<<<1, 4, 0, stream>>>(bcnt, bexc, ncnt, NB2);
  compscat<<<NB2, 256, 0, stream>>>(involved, bexc, nlist, cidx, NB2, N);

  // CSR build
  scan1<<<NB, 256, 0, stream>>>(deg_pd, row_ptr, bsums, M);
  scan2<<<1, 256, 0, stream>>>(bsums, NB);
  scan3<<<NB, 256, 0, stream>>>(row_ptr, bsums, M);
  fillk<<<egrid, 256, 0, stream>>>(ntime, eidx, row_ptr, col, minp, up, N, E);

  for (int p = 0; p < P; ++p) {
    const int* nlp = nlist + (size_t)p * N;
    const int* pc  = ncnt + p;
    const int* cm  = cidx + (size_t)p * N;
    aggk<<<agrid, 256, 0, stream>>>(x_bf, agg_bf, row_ptr, deg_pd, col, nlp, pc,
        nullptr, p, N);
    gemm_mfma<<<ggrid, 256, 0, stream>>>(x_bf, agg_bf, wt,
        bias, lng, lnb, h_bf, nullptr, nullptr, nlp, pc, 0, nseed);
    aggk<<<agrid, 256, 0, stream>>>(h_bf, agg_bf, row_ptr, deg_pd, col, nlp, pc,
        cm, p, N);
    gemm_mfma<<<ggrid, 256, 0, stream>>>(h_bf, agg_bf, wt + 32768,
        bias + CD, lng + CD, lnb + CD, nullptr, x32, x_bf, nlp, pc, 1, nseed);
  }
  headk<<<(nseed + 3) / 4, 256, 0, stream>>>(x32, headw, headb, (float*)d_out, nseed);
}

// Round 5
// 654.186 us; speedup vs baseline: 1.4144x; 1.0675x over previous
//
#include <hip/hip_runtime.h>

// Temporal GraphSAGE, P=4 periods, C=128, L=2 (reference constants).
// R10: byte-store involvement flags. R9 PMC: histk WRITE_SIZE=56.2MB =
// 1.8M atomics x 32B write-through at the coherence point (76 us, HBM-write
// bound). atomicOr on involved needs no RMW (all writers store 1) -> plain
// byte stores into inv[p][node] (write-BACK, ~1MB dirty), keeping only the
// 600K deg atomicAdds (19MB). Also folded ncntk into compscat and x32prep
// into xprep (fewer dispatches).
// Carried: permuted channel layout pi(c)=(c&15)*8+(c>>4) everywhere bf16;
// compact h rows; LDS weight panel + full A-prefetch in gemm.

#define CD 128

typedef __attribute__((ext_vector_type(8))) short s16x8;
typedef __attribute__((ext_vector_type(4))) float f32x4;

static __device__ __forceinline__ unsigned short f2bf(float f) {
  unsigned u = __float_as_uint(f);
  u += 0x7FFF + ((u >> 16) & 1);   // round-to-nearest-even
  return (unsigned short)(u >> 16);
}
static __device__ __forceinline__ float bf2f(unsigned us) {
  return __uint_as_float(us << 16);
}

// ---- histogram: per-(period,dst) degree (atomic) + involvement (plain bytes) ----
__global__ __launch_bounds__(256) void histk(const int* __restrict__ ntime,
    const int* __restrict__ eidx, int* __restrict__ deg_pd,
    unsigned char* __restrict__ inv,
    const int* __restrict__ minp, const int* __restrict__ up, int N, int E) {
  int e = blockIdx.x * 256 + threadIdx.x;
  if (e >= E) return;
  int s = eidx[e], d = eidx[E + e];
  int ts = ntime[s], td = ntime[d];
  int m = ts > td ? ts : td;
  int p = (m - minp[0]) / up[0];
  atomicAdd(&deg_pd[p * N + d], 1);
  inv[(size_t)p * N + s] = 1;   // benign race: all writers store 1
  inv[(size_t)p * N + d] = 1;
}

// ---- compaction pass 1: per-block per-period involved counts ----
__global__ __launch_bounds__(256) void compcnt(const unsigned char* __restrict__ inv,
    int* __restrict__ bcnt, int NB2, int N) {
  int i = blockIdx.x * 256 + threadIdx.x;
  int bits = 0;
  if (i < N)
    bits = (int)inv[i] | ((int)inv[N + i] << 1)
         | ((int)inv[2 * (size_t)N + i] << 2) | ((int)inv[3 * (size_t)N + i] << 3);
  int wv = threadIdx.x >> 6;
  int lane = threadIdx.x & 63;
  __shared__ int wcnt[4][4];   // [period][wave]
#pragma unroll
  for (int p = 0; p < 4; ++p) {
    unsigned long long m = __ballot((bits >> p) & 1);
    if (lane == 0) wcnt[p][wv] = __popcll(m);
  }
  __syncthreads();
  if (threadIdx.x < 4) {
    int p = threadIdx.x;
    bcnt[p * NB2 + blockIdx.x] = wcnt[p][0] + wcnt[p][1] + wcnt[p][2] + wcnt[p][3];
  }
}

// ---- compaction pass 3: deterministic scatter + inverse map + ncnt totals ----
__global__ __launch_bounds__(256) void compscat(const unsigned char* __restrict__ inv,
    const int* __restrict__ bcnt, const int* __restrict__ bexc,
    int* __restrict__ nlist, int* __restrict__ cidx, int* __restrict__ ncnt,
    int NB2, int N) {
  int i = blockIdx.x * 256 + threadIdx.x;
  int bits = 0;
  if (i < N)
    bits = (int)inv[i] | ((int)inv[N + i] << 1)
         | ((int)inv[2 * (size_t)N + i] << 2) | ((int)inv[3 * (size_t)N + i] << 3);
  if (blockIdx.x == 0 && threadIdx.x < 4) {
    int p = threadIdx.x;
    ncnt[p] = bexc[p * NB2 + NB2 - 1] + bcnt[p * NB2 + NB2 - 1] - bexc[p * NB2];
  }
  int wv = threadIdx.x >> 6;
  int lane = threadIdx.x & 63;
  unsigned long long lanes_below = (lane == 0) ? 0ull : ((~0ull) >> (64 - lane));
  __shared__ int wcnt[4][4];
  unsigned long long mm[4];
#pragma unroll
  for (int p = 0; p < 4; ++p) {
    mm[p] = __ballot((bits >> p) & 1);
    if (lane == 0) wcnt[p][wv] = __popcll(mm[p]);
  }
  __syncthreads();
#pragma unroll
  for (int p = 0; p < 4; ++p) {
    if (!((bits >> p) & 1)) continue;
    int wpre = (wv > 0 ? wcnt[p][0] : 0) + (wv > 1 ? wcnt[p][1] : 0)
             + (wv > 2 ? wcnt[p][2] : 0);
    int base = bexc[p * NB2 + blockIdx.x] - bexc[p * NB2];
    int pos = base + wpre + __popcll(mm[p] & lanes_below);
    nlist[p * N + pos] = i;
    cidx[p * N + i] = pos;
  }
}

// ---- exclusive scan (3-phase) ----
__global__ __launch_bounds__(256) void scan1(const int* __restrict__ in,
    int* __restrict__ out, int* __restrict__ bsums, int M) {
  __shared__ int lds[256];
  int tid = threadIdx.x;
  int base = blockIdx.x * 1024 + tid * 4;
  int v0 = base + 0 < M ? in[base + 0] : 0;
  int v1 = base + 1 < M ? in[base + 1] : 0;
  int v2 = base + 2 < M ? in[base + 2] : 0;
  int v3 = base + 3 < M ? in[base + 3] : 0;
  int s = v0 + v1 + v2 + v3;
  lds[tid] = s;
  __syncthreads();
  for (int off = 1; off < 256; off <<= 1) {
    int t = tid >= off ? lds[tid - off] : 0;
    __syncthreads();
    lds[tid] += t;
    __syncthreads();
  }
  int run = lds[tid] - s;
  if (base + 0 < M) out[base + 0] = run; run += v0;
  if (base + 1 < M) out[base + 1] = run; run += v1;
  if (base + 2 < M) out[base + 2] = run; run += v2;
  if (base + 3 < M) out[base + 3] = run;
  if (tid == 255) bsums[blockIdx.x] = lds[255];
}

__global__ __launch_bounds__(256) void scan2(int* __restrict__ b, int M) {
  __shared__ int lds[256];
  int tid = threadIdx.x;
  int base = tid * 4;
  int v0 = base + 0 < M ? b[base + 0] : 0;
  int v1 = base + 1 < M ? b[base + 1] : 0;
  int v2 = base + 2 < M ? b[base + 2] : 0;
  int v3 = base + 3 < M ? b[base + 3] : 0;
  int s = v0 + v1 + v2 + v3;
  lds[tid] = s;
  __syncthreads();
  for (int off = 1; off < 256; off <<= 1) {
    int t = tid >= off ? lds[tid - off] : 0;
    __syncthreads();
    lds[tid] += t;
    __syncthreads();
  }
  int run = lds[tid] - s;
  if (base + 0 < M) b[base + 0] = run; run += v0;
  if (base + 1 < M) b[base + 1] = run; run += v1;
  if (base + 2 < M) b[base + 2] = run; run += v2;
  if (base + 3 < M) b[base + 3] = run;
}

__global__ __launch_bounds__(256) void scan3(int* __restrict__ out,
    const int* __restrict__ bsums, int M) {
  int add = bsums[blockIdx.x];
  int idx = blockIdx.x * 1024 + threadIdx.x;
#pragma unroll
  for (int k = 0; k < 4; ++k) {
    int i = idx + k * 256;
    if (i < M) out[i] += add;
  }
}

// ---- fill CSR col array; row_ptr doubles as cursor ----
__global__ __launch_bounds__(256) void fillk(const int* __restrict__ ntime,
    const int* __restrict__ eidx, int* __restrict__ row_ptr, int* __restrict__ col,
    const int* __restrict__ minp, const int* __restrict__ up, int N, int E) {
  int e = blockIdx.x * 256 + threadIdx.x;
  if (e >= E) return;
  int s = eidx[e], d = eidx[E + e];
  int ts = ntime[s], td = ntime[d];
  int m = ts > td ? ts : td;
  int p = (m - minp[0]) / up[0];
  int pos = atomicAdd(&row_ptr[p * N + d], 1);
  col[pos] = s;
}

// ---- weights: bf16, fragment-linear, K-rows PERMUTED to match pi-layout ----
__global__ __launch_bounds__(256) void wprep(const float* __restrict__ wroot,
    const float* __restrict__ wnbr, unsigned short* __restrict__ wt, int total) {
  int t = blockIdx.x * 256 + threadIdx.x;
  if (t >= total) return;
  int l = t >> 12;
  int rem = t & 4095;
  int q = rem >> 7;
  int n = rem & 127;
  const float* src = (q < 16) ? (wroot + l * CD * CD) : (wnbr + l * CD * CD);
  int qh = q & 15;
  unsigned short o[8];
#pragma unroll
  for (int j = 0; j < 8; ++j) {
    int kp = qh * 8 + j;                 // permuted k within half
    int kt = (kp & 7) * 16 + (kp >> 3);  // true k
    o[j] = f2bf(src[kt * CD + n]);
  }
  uint4 pk;
  pk.x = (unsigned)o[0] | ((unsigned)o[1] << 16);
  pk.y = (unsigned)o[2] | ((unsigned)o[3] << 16);
  pk.z = (unsigned)o[4] | ((unsigned)o[5] << 16);
  pk.w = (unsigned)o[6] | ((unsigned)o[7] << 16);
  *(uint4*)(wt + (size_t)l * 32768 + ((size_t)q * CD + n) * 8) = pk;
}

// ---- x_bf init (permuted layout) + fp32 seed mirror ----
__global__ __launch_bounds__(256) void xprep(const float* __restrict__ x,
    unsigned short* __restrict__ xb, float* __restrict__ x32, int nseed, int total) {
  int t = blockIdx.x * 256 + threadIdx.x;
  if (t >= total) return;            // total = N*16
  int row = t >> 4, j = t & 15;
  const float* xp = x + (size_t)row * CD + j;
  bool seed = row < nseed;
  float* x3 = x32 + (size_t)row * CD + j;
  unsigned short o[8];
#pragma unroll
  for (int tt = 0; tt < 8; ++tt) {
    float v = xp[tt * 16];
    o[tt] = f2bf(v);
    if (seed) x3[tt * 16] = v;
  }
  uint4 pk;
  pk.x = (unsigned)o[0] | ((unsigned)o[1] << 16);
  pk.y = (unsigned)o[2] | ((unsigned)o[3] << 16);
  pk.z = (unsigned)o[4] | ((unsigned)o[5] << 16);
  pk.w = (unsigned)o[6] | ((unsigned)o[7] << 16);
  *(uint4*)(xb + (size_t)row * CD + j * 8) = pk;
}

// ---- pull aggregation over compact involved list ----
__global__ __launch_bounds__(256) void aggk(const unsigned short* __restrict__ hbf,
    unsigned short* __restrict__ aggbf, const int* __restrict__ row_ptr,
    const int* __restrict__ deg_pd, const int* __restrict__ col,
    const int* __restrict__ nlp, const int* __restrict__ pcnt,
    const int* __restrict__ cmap, int p, int N) {
  int cnt = pcnt[0];
  int gi = blockIdx.x * 16 + (threadIdx.x >> 4);
  if (gi >= cnt) return;
  int d = nlp[gi];
  int lane = threadIdx.x & 15;
  int key = p * N + d;
  int dg = deg_pd[key];
  uint4 outv = make_uint4(0u, 0u, 0u, 0u);
  if (dg > 0) {
    int start = row_ptr[key] - dg;
    float a[8];
#pragma unroll
    for (int i = 0; i < 8; ++i) a[i] = 0.f;
    for (int j = 0; j < dg; ++j) {
      int s = col[start + j];
      int r = cmap ? cmap[s] : s;
      uint4 rv = *(const uint4*)(hbf + (size_t)r * CD + lane * 8);
      a[0] += bf2f(rv.x & 0xffffu); a[1] += bf2f(rv.x >> 16);
      a[2] += bf2f(rv.y & 0xffffu); a[3] += bf2f(rv.y >> 16);
      a[4] += bf2f(rv.z & 0xffffu); a[5] += bf2f(rv.z >> 16);
      a[6] += bf2f(rv.w & 0xffffu); a[7] += bf2f(rv.w >> 16);
    }
    float sc = 1.0f / (float)dg;
    outv.x = (unsigned)f2bf(a[0] * sc) | ((unsigned)f2bf(a[1] * sc) << 16);
    outv.y = (unsigned)f2bf(a[2] * sc) | ((unsigned)f2bf(a[3] * sc) << 16);
    outv.z = (unsigned)f2bf(a[4] * sc) | ((unsigned)f2bf(a[5] * sc) << 16);
    outv.w = (unsigned)f2bf(a[6] * sc) | ((unsigned)f2bf(a[7] * sc) << 16);
  }
  *(uint4*)(aggbf + (size_t)gi * CD + lane * 8) = outv;
}

// ---- MFMA GEMM + bias + LN; vectorized epilogue via permuted layout ----
__global__ __launch_bounds__(256, 2) void gemm_mfma(
    const unsigned short* __restrict__ A1, const unsigned short* __restrict__ A2,
    const unsigned short* __restrict__ wt,
    const float* __restrict__ bias, const float* __restrict__ lng,
    const float* __restrict__ lnb,
    unsigned short* __restrict__ hout,
    float* __restrict__ x32, unsigned short* __restrict__ xbf,
    const int* __restrict__ nlp, const int* __restrict__ pcnt,
    int mode, int nseed) {
  int cnt = pcnt[0];
  int rbase = blockIdx.x * 128;
  if (rbase >= cnt) return;

  __shared__ unsigned short Blds[32768];   // 64 KB: whole layer weight panel
  {
    const uint4* src = (const uint4*)wt;
    uint4* dst = (uint4*)Blds;
#pragma unroll
    for (int i = 0; i < 16; ++i) dst[threadIdx.x + i * 256] = src[threadIdx.x + i * 256];
  }
  __syncthreads();

  int tid = threadIdx.x;
  int w = tid >> 6;
  int lane = tid & 63;
  int l15 = lane & 15;
  int quad = lane >> 4;

  // per-lane A rows (clamped; duplicate work beyond cnt discarded in epilogue)
  const unsigned short* base1[2];
  const unsigned short* base2[2];
#pragma unroll
  for (int rt = 0; rt < 2; ++rt) {
    int ii = rbase + w * 32 + rt * 16 + l15;
    ii = ii < cnt ? ii : cnt - 1;
    int arow = (mode == 0) ? nlp[ii] : ii;   // layer1: node gather; layer2: stream
    base1[rt] = A1 + (size_t)arow * CD;
    base2[rt] = A2 + (size_t)ii * CD;
  }

  // prefetch ALL A fragments (16 x 16B = 64 VGPRs) up front
  s16x8 af[4][2][2];
#pragma unroll
  for (int kc = 0; kc < 4; ++kc) {
    int koff = (kc & 1) * 64;
#pragma unroll
    for (int ks = 0; ks < 2; ++ks) {
      int kb = (ks * 4 + quad) * 8;
#pragma unroll
      for (int rt = 0; rt < 2; ++rt)
        af[kc][ks][rt] = *(const s16x8*)((kc < 2 ? base1[rt] : base2[rt]) + koff + kb);
    }
  }

  f32x4 acc[2][8];
#pragma unroll
  for (int rt = 0; rt < 2; ++rt)
#pragma unroll
    for (int ct = 0; ct < 8; ++ct) acc[rt][ct] = (f32x4)(0.f);

#pragma unroll
  for (int kc = 0; kc < 4; ++kc) {
#pragma unroll
    for (int ks = 0; ks < 2; ++ks) {
      int q = kc * 8 + ks * 4 + quad;        // global 16B k-block in [0,32)
      s16x8 bfr[8];
#pragma unroll
      for (int ct = 0; ct < 8; ++ct)
        bfr[ct] = *(const s16x8*)&Blds[((size_t)q * CD + l15) * 8 + (size_t)ct * 128];
#pragma unroll
      for (int rt = 0; rt < 2; ++rt)
#pragma unroll
        for (int ct = 0; ct < 8; ++ct)
          acc[rt][ct] = __builtin_amdgcn_mfma_f32_16x16x32_bf16(
              af[kc][ks][rt], bfr[ct], acc[rt][ct], 0, 0, 0);
    }
  }

  // epilogue: bias + LayerNorm across the 16-lane row group (true col = ct*16+l15)
  float bb[8], gg[8], eb[8];
#pragma unroll
  for (int ct = 0; ct < 8; ++ct) {
    int c = ct * 16 + l15;
    bb[ct] = bias[c]; gg[ct] = lng[c]; eb[ct] = lnb[c];
  }
#pragma unroll
  for (int rt = 0; rt < 2; ++rt) {
#pragma unroll
    for (int reg = 0; reg < 4; ++reg) {
      int ridx = rbase + w * 32 + rt * 16 + quad * 4 + reg;
      float vals[8];
      float s = 0.f, ss = 0.f;
#pragma unroll
      for (int ct = 0; ct < 8; ++ct) {
        float v = acc[rt][ct][reg] + bb[ct];
        vals[ct] = v;
        s += v; ss += v * v;
      }
#pragma unroll
      for (int m = 1; m <= 8; m <<= 1) {
        s  += __shfl_xor(s, m, 64);
        ss += __shfl_xor(ss, m, 64);
      }
      float mu  = s * (1.0f / CD);
      float var = ss * (1.0f / CD) - mu * mu;
      float rs  = rsqrtf(var + 1e-5f);
      if (ridx < cnt) {
        float o[8];
#pragma unroll
        for (int ct = 0; ct < 8; ++ct) o[ct] = (vals[ct] - mu) * rs * gg[ct] + eb[ct];
        if (mode == 0) {
          uint4 pk;
          pk.x = (unsigned)f2bf(fmaxf(o[0], 0.f)) | ((unsigned)f2bf(fmaxf(o[1], 0.f)) << 16);
          pk.y = (unsigned)f2bf(fmaxf(o[2], 0.f)) | ((unsigned)f2bf(fmaxf(o[3], 0.f)) << 16);
          pk.z = (unsigned)f2bf(fmaxf(o[4], 0.f)) | ((unsigned)f2bf(fmaxf(o[5], 0.f)) << 16);
          pk.w = (unsigned)f2bf(fmaxf(o[6], 0.f)) | ((unsigned)f2bf(fmaxf(o[7], 0.f)) << 16);
          *(uint4*)(hout + (size_t)ridx * CD + l15 * 8) = pk;   // compact, sequential
        } else {
          int node = nlp[ridx];
          unsigned short* xp = xbf + (size_t)node * CD + l15 * 8;
          uint4 old = *(const uint4*)xp;
          float xn0 = bf2f(old.x & 0xffffu) + o[0], xn1 = bf2f(old.x >> 16) + o[1];
          float xn2 = bf2f(old.y & 0xffffu) + o[2], xn3 = bf2f(old.y >> 16) + o[3];
          float xn4 = bf2f(old.z & 0xffffu) + o[4], xn5 = bf2f(old.z >> 16) + o[5];
          float xn6 = bf2f(old.w & 0xffffu) + o[6], xn7 = bf2f(old.w >> 16) + o[7];
          uint4 pk;
          pk.x = (unsigned)f2bf(xn0) | ((unsigned)f2bf(xn1) << 16);
          pk.y = (unsigned)f2bf(xn2) | ((unsigned)f2bf(xn3) << 16);
          pk.z = (unsigned)f2bf(xn4) | ((unsigned)f2bf(xn5) << 16);
          pk.w = (unsigned)f2bf(xn6) | ((unsigned)f2bf(xn7) << 16);
          *(uint4*)xp = pk;
          if (node < nseed) {
            float* x3 = x32 + (size_t)node * CD + l15;
#pragma unroll
            for (int ct = 0; ct < 8; ++ct) x3[ct * 16] += o[ct];
          }
        }
      }
    }
  }
}

// ---- head (reads fp32 seed mirror, original layout) ----
__global__ __launch_bounds__(256) void headk(const float* __restrict__ x,
    const float* __restrict__ hw, const float* __restrict__ hb,
    float* __restrict__ out, int seeds) {
  int wave = threadIdx.x >> 6;
  int lane = threadIdx.x & 63;
  int row = blockIdx.x * 4 + wave;
  if (row >= seeds) return;
  const float* xp = x + (size_t)row * CD;
  float v = xp[lane] * hw[lane] + xp[64 + lane] * hw[64 + lane];
#pragma unroll
  for (int m = 1; m < 64; m <<= 1) v += __shfl_xor(v, m, 64);
  if (lane == 0) out[row] = v + hb[0];
}

extern "C" void kernel_launch(void* const* d_in, const int* in_sizes, int n_in,
                              void* d_out, int out_size, void* d_ws, size_t ws_size,
                              hipStream_t stream) {
  const float* x     = (const float*)d_in[0];
  const int*   ntime = (const int*)d_in[1];
  const int*   eidx  = (const int*)d_in[2];
  const float* wroot = (const float*)d_in[3];
  const float* wnbr  = (const float*)d_in[4];
  const float* bias  = (const float*)d_in[5];
  const float* lng   = (const float*)d_in[6];
  const float* lnb   = (const float*)d_in[7];
  const float* headw = (const float*)d_in[8];
  const float* headb = (const float*)d_in[9];
  const int*   minp  = (const int*)d_in[10];
  const int*   up    = (const int*)d_in[12];

  int N = in_sizes[0] / CD;
  int E = in_sizes[2] / 2;
  const int P = 4;
  int M = P * N;
  int nseed = out_size;   // OUT=1 per reference

  size_t off = 0;
  auto alloc = [&](size_t bytes) {
    void* p = (char*)d_ws + off;
    off += (bytes + 255) & ~(size_t)255;
    return p;
  };
  unsigned short* x_bf   = (unsigned short*)alloc((size_t)N * CD * 2);
  unsigned short* h_bf   = (unsigned short*)alloc((size_t)N * CD * 2);   // compact rows
  unsigned short* agg_bf = (unsigned short*)alloc((size_t)N * CD * 2);   // compact rows
  float*          x32    = (float*)alloc((size_t)nseed * CD * 4);
  unsigned short* wt     = (unsigned short*)alloc(2 * 32768 * 2);
  int* deg_pd   = (int*)alloc((size_t)M * 4);
  int* row_ptr  = (int*)alloc((size_t)M * 4);
  int* col      = (int*)alloc((size_t)E * 4);
  unsigned char* inv = (unsigned char*)alloc((size_t)M);   // [p][node] flags
  int* nlist    = (int*)alloc((size_t)M * 4);
  int* cidx     = (int*)alloc((size_t)M * 4);
  int* ncnt     = (int*)alloc(256);
  int* bsums    = (int*)alloc(4096);

  int NB2 = (N + 255) / 256;               // compaction blocks
  int M2 = 4 * NB2;                        // bcnt/bexc length
  int* bcnt = (int*)alloc((size_t)M2 * 4);
  int* bexc = (int*)alloc((size_t)M2 * 4);
  (void)ws_size;

  hipMemsetAsync(deg_pd, 0, (size_t)M * 4, stream);
  hipMemsetAsync(inv, 0, (size_t)M, stream);

  int egrid = (E + 255) / 256;
  int NB = (M + 1023) / 1024;
  int NBc = (M2 + 1023) / 1024;
  int ggrid = (N + 127) / 128;
  int agrid = (N + 15) / 16;

  xprep<<<(N * 16 + 255) / 256, 256, 0, stream>>>(x, x_bf, x32, nseed, N * 16);
  wprep<<<(8192 + 255) / 256, 256, 0, stream>>>(wroot, wnbr, wt, 8192);
  histk<<<egrid, 256, 0, stream>>>(ntime, eidx, deg_pd, inv, minp, up, N, E);

  // compaction: count -> scan -> scatter (+ node->gi map, + ncnt totals)
  compcnt<<<NB2, 256, 0, stream>>>(inv, bcnt, NB2, N);
  scan1<<<NBc, 256, 0, stream>>>(bcnt, bexc, bsums, M2);
  scan2<<<1, 256, 0, stream>>>(bsums, NBc);
  scan3<<<NBc, 256, 0, stream>>>(bexc, bsums, M2);
  compscat<<<NB2, 256, 0, stream>>>(inv, bcnt, bexc, nlist, cidx, ncnt, NB2, N);

  // CSR build
  scan1<<<NB, 256, 0, stream>>>(deg_pd, row_ptr, bsums, M);
  scan2<<<1, 256, 0, stream>>>(bsums, NB);
  scan3<<<NB, 256, 0, stream>>>(row_ptr, bsums, M);
  fillk<<<egrid, 256, 0, stream>>>(ntime, eidx, row_ptr, col, minp, up, N, E);

  for (int p = 0; p < P; ++p) {
    const int* nlp = nlist + (size_t)p * N;
    const int* pc  = ncnt + p;
    const int* cm  = cidx + (size_t)p * N;
    aggk<<<agrid, 256, 0, stream>>>(x_bf, agg_bf, row_ptr, deg_pd, col, nlp, pc,
        nullptr, p, N);
    gemm_mfma<<<ggrid, 256, 0, stream>>>(x_bf, agg_bf, wt,
        bias, lng, lnb, h_bf, nullptr, nullptr, nlp, pc, 0, nseed);
    aggk<<<agrid, 256, 0, stream>>>(h_bf, agg_bf, row_ptr, deg_pd, col, nlp, pc,
        cm, p, N);
    gemm_mfma<<<ggrid, 256, 0, stream>>>(h_bf, agg_bf, wt + 32768,
        bias + CD, lng + CD, lnb + CD, nullptr, x32, x_bf, nlp, pc, 1, nseed);
  }
  headk<<<(nseed + 3) / 4, 256, 0, stream>>>(x32, headw, headb, (float*)d_out, nseed);
}

// Round 8
// 620.972 us; speedup vs baseline: 1.4900x; 1.0535x over previous
//
#include <hip/hip_runtime.h>

// Temporal GraphSAGE, P=4 periods, C=128, L=2 (reference constants).
// R13: fused aggregate+GEMM with R10's EXACT ordering + arithmetic.
// R11/R12 post-mortem: the fused math was bitwise-correct; what changed the
// absmax (0.0625 -> 0.156/0.25, threshold 0.2225) was the CSR bucket
// ORDERING mechanism (histk-erank vs fillk-cursor) perturbing bf16 rounding
// ties in the neighbor means. R13 restores R10's cursor-atomic fillk and
// f32 ascending-order accumulation with start = row_ptr[key]-dg, making the
// fused gather BITWISE identical to R10's aggk output (absmax 0.0625,
// 6 rounds stable) while keeping R11's speed (no aggk, no agg_bf trip).
// Carried: permuted channel layout pi(c)=(c&15)*8+(c>>4); compact h rows;
// LDS weight panel + deferred barrier; byte involvement flags; scan-based
// compaction; remapk (period bounds via post-cursor bucket ends).

#define CD 128

typedef __attribute__((ext_vector_type(8))) short s16x8;
typedef __attribute__((ext_vector_type(4))) float f32x4;

static __device__ __forceinline__ unsigned short f2bf(float f) {
  unsigned u = __float_as_uint(f);
  u += 0x7FFF + ((u >> 16) & 1);   // round-to-nearest-even
  return (unsigned short)(u >> 16);
}
static __device__ __forceinline__ float bf2f(unsigned us) {
  return __uint_as_float(us << 16);
}
static __device__ __forceinline__ void acc8(float* a, uint4 v) {
  a[0] += bf2f(v.x & 0xffffu); a[1] += bf2f(v.x >> 16);
  a[2] += bf2f(v.y & 0xffffu); a[3] += bf2f(v.y >> 16);
  a[4] += bf2f(v.z & 0xffffu); a[5] += bf2f(v.z >> 16);
  a[6] += bf2f(v.w & 0xffffu); a[7] += bf2f(v.w >> 16);
}
static __device__ __forceinline__ s16x8 pack8(const float* a, float sc) {
  s16x8 r;
#pragma unroll
  for (int j = 0; j < 8; ++j) r[j] = (short)f2bf(a[j] * sc);
  return r;
}

// ---- histogram: per-(period,dst) degree (atomic) + involvement bytes ----
// (R10 version: no erank — ordering mechanism must stay bit-compatible)
__global__ __launch_bounds__(256) void histk(const int* __restrict__ ntime,
    const int* __restrict__ eidx, int* __restrict__ deg_pd,
    unsigned char* __restrict__ inv,
    const int* __restrict__ minp, const int* __restrict__ up, int N, int E) {
  int e = blockIdx.x * 256 + threadIdx.x;
  if (e >= E) return;
  int s = eidx[e], d = eidx[E + e];
  int ts = ntime[s], td = ntime[d];
  int m = ts > td ? ts : td;
  int p = (m - minp[0]) / up[0];
  atomicAdd(&deg_pd[p * N + d], 1);
  inv[(size_t)p * N + s] = 1;   // benign race: all writers store 1
  inv[(size_t)p * N + d] = 1;
}

// ---- compaction pass 1: per-block per-period involved counts ----
__global__ __launch_bounds__(256) void compcnt(const unsigned char* __restrict__ inv,
    int* __restrict__ bcnt, int NB2, int N) {
  int i = blockIdx.x * 256 + threadIdx.x;
  int bits = 0;
  if (i < N)
    bits = (int)inv[i] | ((int)inv[N + i] << 1)
         | ((int)inv[2 * (size_t)N + i] << 2) | ((int)inv[3 * (size_t)N + i] << 3);
  int wv = threadIdx.x >> 6;
  int lane = threadIdx.x & 63;
  __shared__ int wcnt[4][4];   // [period][wave]
#pragma unroll
  for (int p = 0; p < 4; ++p) {
    unsigned long long m = __ballot((bits >> p) & 1);
    if (lane == 0) wcnt[p][wv] = __popcll(m);
  }
  __syncthreads();
  if (threadIdx.x < 4) {
    int p = threadIdx.x;
    bcnt[p * NB2 + blockIdx.x] = wcnt[p][0] + wcnt[p][1] + wcnt[p][2] + wcnt[p][3];
  }
}

// ---- compaction pass 3: deterministic scatter + inverse map + ncnt totals ----
__global__ __launch_bounds__(256) void compscat(const unsigned char* __restrict__ inv,
    const int* __restrict__ bcnt, const int* __restrict__ bexc,
    int* __restrict__ nlist, int* __restrict__ cidx, int* __restrict__ ncnt,
    int NB2, int N) {
  int i = blockIdx.x * 256 + threadIdx.x;
  int bits = 0;
  if (i < N)
    bits = (int)inv[i] | ((int)inv[N + i] << 1)
         | ((int)inv[2 * (size_t)N + i] << 2) | ((int)inv[3 * (size_t)N + i] << 3);
  if (blockIdx.x == 0 && threadIdx.x < 4) {
    int p = threadIdx.x;
    ncnt[p] = bexc[p * NB2 + NB2 - 1] + bcnt[p * NB2 + NB2 - 1] - bexc[p * NB2];
  }
  int wv = threadIdx.x >> 6;
  int lane = threadIdx.x & 63;
  unsigned long long lanes_below = (lane == 0) ? 0ull : ((~0ull) >> (64 - lane));
  __shared__ int wcnt[4][4];
  unsigned long long mm[4];
#pragma unroll
  for (int p = 0; p < 4; ++p) {
    mm[p] = __ballot((bits >> p) & 1);
    if (lane == 0) wcnt[p][wv] = __popcll(mm[p]);
  }
  __syncthreads();
#pragma unroll
  for (int p = 0; p < 4; ++p) {
    if (!((bits >> p) & 1)) continue;
    int wpre = (wv > 0 ? wcnt[p][0] : 0) + (wv > 1 ? wcnt[p][1] : 0)
             + (wv > 2 ? wcnt[p][2] : 0);
    int base = bexc[p * NB2 + blockIdx.x] - bexc[p * NB2];
    int pos = base + wpre + __popcll(mm[p] & lanes_below);
    nlist[p * N + pos] = i;
    cidx[p * N + i] = pos;
  }
}

// ---- exclusive scan (3-phase) ----
__global__ __launch_bounds__(256) void scan1(const int* __restrict__ in,
    int* __restrict__ out, int* __restrict__ bsums, int M) {
  __shared__ int lds[256];
  int tid = threadIdx.x;
  int base = blockIdx.x * 1024 + tid * 4;
  int v0 = base + 0 < M ? in[base + 0] : 0;
  int v1 = base + 1 < M ? in[base + 1] : 0;
  int v2 = base + 2 < M ? in[base + 2] : 0;
  int v3 = base + 3 < M ? in[base + 3] : 0;
  int s = v0 + v1 + v2 + v3;
  lds[tid] = s;
  __syncthreads();
  for (int off = 1; off < 256; off <<= 1) {
    int t = tid >= off ? lds[tid - off] : 0;
    __syncthreads();
    lds[tid] += t;
    __syncthreads();
  }
  int run = lds[tid] - s;
  if (base + 0 < M) out[base + 0] = run; run += v0;
  if (base + 1 < M) out[base + 1] = run; run += v1;
  if (base + 2 < M) out[base + 2] = run; run += v2;
  if (base + 3 < M) out[base + 3] = run;
  if (tid == 255) bsums[blockIdx.x] = lds[255];
}

__global__ __launch_bounds__(256) void scan2(int* __restrict__ b, int M) {
  __shared__ int lds[256];
  int tid = threadIdx.x;
  int base = tid * 4;
  int v0 = base + 0 < M ? b[base + 0] : 0;
  int v1 = base + 1 < M ? b[base + 1] : 0;
  int v2 = base + 2 < M ? b[base + 2] : 0;
  int v3 = base + 3 < M ? b[base + 3] : 0;
  int s = v0 + v1 + v2 + v3;
  lds[tid] = s;
  __syncthreads();
  for (int off = 1; off < 256; off <<= 1) {
    int t = tid >= off ? lds[tid - off] : 0;
    __syncthreads();
    lds[tid] += t;
    __syncthreads();
  }
  int run = lds[tid] - s;
  if (base + 0 < M) b[base + 0] = run; run += v0;
  if (base + 1 < M) b[base + 1] = run; run += v1;
  if (base + 2 < M) b[base + 2] = run; run += v2;
  if (base + 3 < M) b[base + 3] = run;
}

__global__ __launch_bounds__(256) void scan3(int* __restrict__ out,
    const int* __restrict__ bsums, int M) {
  int add = bsums[blockIdx.x];
  int idx = blockIdx.x * 1024 + threadIdx.x;
#pragma unroll
  for (int k = 0; k < 4; ++k) {
    int i = idx + k * 256;
    if (i < M) out[i] += add;
  }
}

// ---- fill CSR col array; row_ptr doubles as cursor (R10 mechanism) ----
__global__ __launch_bounds__(256) void fillk(const int* __restrict__ ntime,
    const int* __restrict__ eidx, int* __restrict__ row_ptr, int* __restrict__ col,
    const int* __restrict__ minp, const int* __restrict__ up, int N, int E) {
  int e = blockIdx.x * 256 + threadIdx.x;
  if (e >= E) return;
  int s = eidx[e], d = eidx[E + e];
  int ts = ntime[s], td = ntime[d];
  int m = ts > td ? ts : td;
  int p = (m - minp[0]) / up[0];
  int pos = atomicAdd(&row_ptr[p * N + d], 1);
  col[pos] = s;
}

// ---- translate layer2 sources: col (node id) -> col2 (compact gi) ----
// row_ptr is post-cursor (bucket ENDS): period p ends at row_ptr[(p+1)*N-1].
__global__ __launch_bounds__(256) void remapk(const int* __restrict__ col,
    int* __restrict__ col2, const int* __restrict__ cidx,
    const int* __restrict__ row_ptr, int N, int E) {
  int i = blockIdx.x * 256 + threadIdx.x;
  if (i >= E) return;
  int p = (i >= row_ptr[N - 1]) + (i >= row_ptr[2 * N - 1]) + (i >= row_ptr[3 * N - 1]);
  col2[i] = cidx[(size_t)p * N + col[i]];
}

// ---- weights: bf16, fragment-linear, K-rows PERMUTED to match pi-layout ----
__global__ __launch_bounds__(256) void wprep(const float* __restrict__ wroot,
    const float* __restrict__ wnbr, unsigned short* __restrict__ wt, int total) {
  int t = blockIdx.x * 256 + threadIdx.x;
  if (t >= total) return;
  int l = t >> 12;
  int rem = t & 4095;
  int q = rem >> 7;
  int n = rem & 127;
  const float* src = (q < 16) ? (wroot + l * CD * CD) : (wnbr + l * CD * CD);
  int qh = q & 15;
  unsigned short o[8];
#pragma unroll
  for (int j = 0; j < 8; ++j) {
    int kp = qh * 8 + j;                 // permuted k within half
    int kt = (kp & 7) * 16 + (kp >> 3);  // true k
    o[j] = f2bf(src[kt * CD + n]);
  }
  uint4 pk;
  pk.x = (unsigned)o[0] | ((unsigned)o[1] << 16);
  pk.y = (unsigned)o[2] | ((unsigned)o[3] << 16);
  pk.z = (unsigned)o[4] | ((unsigned)o[5] << 16);
  pk.w = (unsigned)o[6] | ((unsigned)o[7] << 16);
  *(uint4*)(wt + (size_t)l * 32768 + ((size_t)q * CD + n) * 8) = pk;
}

// ---- x_bf init (permuted layout) + fp32 seed mirror ----
__global__ __launch_bounds__(256) void xprep(const float* __restrict__ x,
    unsigned short* __restrict__ xb, float* __restrict__ x32, int nseed, int total) {
  int t = blockIdx.x * 256 + threadIdx.x;
  if (t >= total) return;            // total = N*16
  int row = t >> 4, j = t & 15;
  const float* xp = x + (size_t)row * CD + j;
  bool seed = row < nseed;
  float* x3 = x32 + (size_t)row * CD + j;
  unsigned short o[8];
#pragma unroll
  for (int tt = 0; tt < 8; ++tt) {
    float v = xp[tt * 16];
    o[tt] = f2bf(v);
    if (seed) x3[tt * 16] = v;
  }
  uint4 pk;
  pk.x = (unsigned)o[0] | ((unsigned)o[1] << 16);
  pk.y = (unsigned)o[2] | ((unsigned)o[3] << 16);
  pk.z = (unsigned)o[4] | ((unsigned)o[5] << 16);
  pk.w = (unsigned)o[6] | ((unsigned)o[7] << 16);
  *(uint4*)(xb + (size_t)row * CD + j * 8) = pk;
}

// ---- FUSED gather-aggregate + MFMA GEMM + bias + LN ----
// A2 = mean over CSR neighbors, f32-accumulated in ascending CSR order with
// start = row_ptr[key]-dg  ==> bitwise-identical to R10's aggk output.
__global__ __launch_bounds__(256, 2) void gemm_fused(
    const unsigned short* __restrict__ feat,
    const unsigned short* __restrict__ wt,
    const float* __restrict__ bias, const float* __restrict__ lng,
    const float* __restrict__ lnb,
    unsigned short* __restrict__ hout,
    float* __restrict__ x32, unsigned short* __restrict__ xbf,
    const int* __restrict__ nlp, const int* __restrict__ pcnt,
    const int* __restrict__ deg_pd, const int* __restrict__ row_ptr,
    const int* __restrict__ cols,
    int p, int N, int mode, int nseed) {
  int cnt = pcnt[0];
  int rbase = blockIdx.x * 128;
  if (rbase >= cnt) return;

  __shared__ unsigned short Blds[32768];   // 64 KB: whole layer weight panel
  {
    const uint4* src = (const uint4*)wt;
    uint4* dst = (uint4*)Blds;
#pragma unroll
    for (int i = 0; i < 16; ++i) dst[threadIdx.x + i * 256] = src[threadIdx.x + i * 256];
  }
  // barrier deferred until after gather (gather doesn't touch LDS)

  int tid = threadIdx.x;
  int w = tid >> 6;
  int lane = tid & 63;
  int l15 = lane & 15;
  int quad = lane >> 4;

  // per-lane A rows + CSR metadata (clamped; dup work discarded in epilogue)
  int dg_[2], st_[2];
  const unsigned short* b1[2];
#pragma unroll
  for (int rt = 0; rt < 2; ++rt) {
    int ii = rbase + w * 32 + rt * 16 + l15;
    ii = ii < cnt ? ii : cnt - 1;
    int node = nlp[ii];
    int key = p * N + node;
    int dg = deg_pd[key];
    dg_[rt] = dg;
    st_[rt] = row_ptr[key] - dg;          // cursor end - deg = bucket start
    b1[rt] = feat + (size_t)(mode == 0 ? node : ii) * CD;
  }

  s16x8 af[4][2][2];
  // A1 fragments (kc 0..1)
#pragma unroll
  for (int kc = 0; kc < 2; ++kc)
#pragma unroll
    for (int ks = 0; ks < 2; ++ks) {
      int off = kc * 64 + (ks * 4 + quad) * 8;
#pragma unroll
      for (int rt = 0; rt < 2; ++rt)
        af[kc][ks][rt] = *(const s16x8*)(b1[rt] + off);
    }

  // A2 fragments (kc 2..3): fused CSR gather + mean (f32, ascending order)
  int cb = quad * 8;
#pragma unroll
  for (int rt = 0; rt < 2; ++rt) {
    float a0[8], a1[8], a2[8], a3[8];
#pragma unroll
    for (int j = 0; j < 8; ++j) { a0[j] = 0.f; a1[j] = 0.f; a2[j] = 0.f; a3[j] = 0.f; }
    int dg = dg_[rt], st = st_[rt];
    for (int j = 0; j < dg; ++j) {
      int r = cols[st + j];
      const unsigned short* rp = feat + (size_t)r * CD;
      uint4 v0 = *(const uint4*)(rp + cb);
      uint4 v1 = *(const uint4*)(rp + cb + 32);
      uint4 v2 = *(const uint4*)(rp + cb + 64);
      uint4 v3 = *(const uint4*)(rp + cb + 96);
      acc8(a0, v0); acc8(a1, v1); acc8(a2, v2); acc8(a3, v3);
    }
    float sc = dg > 0 ? 1.0f / (float)dg : 0.f;
    af[2][0][rt] = pack8(a0, sc);
    af[2][1][rt] = pack8(a1, sc);
    af[3][0][rt] = pack8(a2, sc);
    af[3][1][rt] = pack8(a3, sc);
  }

  __syncthreads();   // B panel ready (staged during gather)

  f32x4 acc[2][8];
#pragma unroll
  for (int rt = 0; rt < 2; ++rt)
#pragma unroll
    for (int ct = 0; ct < 8; ++ct) acc[rt][ct] = (f32x4)(0.f);

#pragma unroll
  for (int kc = 0; kc < 4; ++kc) {
#pragma unroll
    for (int ks = 0; ks < 2; ++ks) {
      int q = kc * 8 + ks * 4 + quad;        // global 16B k-block in [0,32)
      s16x8 bfr[8];
#pragma unroll
      for (int ct = 0; ct < 8; ++ct)
        bfr[ct] = *(const s16x8*)&Blds[((size_t)q * CD + l15) * 8 + (size_t)ct * 128];
#pragma unroll
      for (int rt = 0; rt < 2; ++rt)
#pragma unroll
        for (int ct = 0; ct < 8; ++ct)
          acc[rt][ct] = __builtin_amdgcn_mfma_f32_16x16x32_bf16(
              af[kc][ks][rt], bfr[ct], acc[rt][ct], 0, 0, 0);
    }
  }

  // epilogue: bias + LayerNorm across the 16-lane row group (true col = ct*16+l15)
  float bb[8], gg[8], eb[8];
#pragma unroll
  for (int ct = 0; ct < 8; ++ct) {
    int c = ct * 16 + l15;
    bb[ct] = bias[c]; gg[ct] = lng[c]; eb[ct] = lnb[c];
  }
#pragma unroll
  for (int rt = 0; rt < 2; ++rt) {
#pragma unroll
    for (int reg = 0; reg < 4; ++reg) {
      int ridx = rbase + w * 32 + rt * 16 + quad * 4 + reg;
      float vals[8];
      float s = 0.f, ss = 0.f;
#pragma unroll
      for (int ct = 0; ct < 8; ++ct) {
        float v = acc[rt][ct][reg] + bb[ct];
        vals[ct] = v;
        s += v; ss += v * v;
      }
#pragma unroll
      for (int m = 1; m <= 8; m <<= 1) {
        s  += __shfl_xor(s, m, 64);
        ss += __shfl_xor(ss, m, 64);
      }
      float mu  = s * (1.0f / CD);
      float var = ss * (1.0f / CD) - mu * mu;
      float rs  = rsqrtf(var + 1e-5f);
      if (ridx < cnt) {
        float o[8];
#pragma unroll
        for (int ct = 0; ct < 8; ++ct) o[ct] = (vals[ct] - mu) * rs * gg[ct] + eb[ct];
        if (mode == 0) {
          uint4 pk;
          pk.x = (unsigned)f2bf(fmaxf(o[0], 0.f)) | ((unsigned)f2bf(fmaxf(o[1], 0.f)) << 16);
          pk.y = (unsigned)f2bf(fmaxf(o[2], 0.f)) | ((unsigned)f2bf(fmaxf(o[3], 0.f)) << 16);
          pk.z = (unsigned)f2bf(fmaxf(o[4], 0.f)) | ((unsigned)f2bf(fmaxf(o[5], 0.f)) << 16);
          pk.w = (unsigned)f2bf(fmaxf(o[6], 0.f)) | ((unsigned)f2bf(fmaxf(o[7], 0.f)) << 16);
          *(uint4*)(hout + (size_t)ridx * CD + l15 * 8) = pk;   // compact, sequential
        } else {
          int node = nlp[ridx];
          unsigned short* xp = xbf + (size_t)node * CD + l15 * 8;
          uint4 old = *(const uint4*)xp;
          float xn0 = bf2f(old.x & 0xffffu) + o[0], xn1 = bf2f(old.x >> 16) + o[1];
          float xn2 = bf2f(old.y & 0xffffu) + o[2], xn3 = bf2f(old.y >> 16) + o[3];
          float xn4 = bf2f(old.z & 0xffffu) + o[4], xn5 = bf2f(old.z >> 16) + o[5];
          float xn6 = bf2f(old.w & 0xffffu) + o[6], xn7 = bf2f(old.w >> 16) + o[7];
          uint4 pk;
          pk.x = (unsigned)f2bf(xn0) | ((unsigned)f2bf(xn1) << 16);
          pk.y = (unsigned)f2bf(xn2) | ((unsigned)f2bf(xn3) << 16);
          pk.z = (unsigned)f2bf(xn4) | ((unsigned)f2bf(xn5) << 16);
          pk.w = (unsigned)f2bf(xn6) | ((unsigned)f2bf(xn7) << 16);
          *(uint4*)xp = pk;
          if (node < nseed) {
            float* x3 = x32 + (size_t)node * CD + l15;
#pragma unroll
            for (int ct = 0; ct < 8; ++ct) x3[ct * 16] += o[ct];
          }
        }
      }
    }
  }
}

// ---- head (reads fp32 seed mirror, original layout) ----
__global__ __launch_bounds__(256) void headk(const float* __restrict__ x,
    const float* __restrict__ hw, const float* __restrict__ hb,
    float* __restrict__ out, int seeds) {
  int wave = threadIdx.x >> 6;
  int lane = threadIdx.x & 63;
  int row = blockIdx.x * 4 + wave;
  if (row >= seeds) return;
  const float* xp = x + (size_t)row * CD;
  float v = xp[lane] * hw[lane] + xp[64 + lane] * hw[64 + lane];
#pragma unroll
  for (int m = 1; m < 64; m <<= 1) v += __shfl_xor(v, m, 64);
  if (lane == 0) out[row] = v + hb[0];
}

extern "C" void kernel_launch(void* const* d_in, const int* in_sizes, int n_in,
                              void* d_out, int out_size, void* d_ws, size_t ws_size,
                              hipStream_t stream) {
  const float* x     = (const float*)d_in[0];
  const int*   ntime = (const int*)d_in[1];
  const int*   eidx  = (const int*)d_in[2];
  const float* wroot = (const float*)d_in[3];
  const float* wnbr  = (const float*)d_in[4];
  const float* bias  = (const float*)d_in[5];
  const float* lng   = (const float*)d_in[6];
  const float* lnb   = (const float*)d_in[7];
  const float* headw = (const float*)d_in[8];
  const float* headb = (const float*)d_in[9];
  const int*   minp  = (const int*)d_in[10];
  const int*   up    = (const int*)d_in[12];

  int N = in_sizes[0] / CD;
  int E = in_sizes[2] / 2;
  const int P = 4;
  int M = P * N;
  int nseed = out_size;   // OUT=1 per reference

  size_t off = 0;
  auto alloc = [&](size_t bytes) {
    void* p = (char*)d_ws + off;
    off += (bytes + 255) & ~(size_t)255;
    return p;
  };
  unsigned short* x_bf = (unsigned short*)alloc((size_t)N * CD * 2);
  unsigned short* h_bf = (unsigned short*)alloc((size_t)N * CD * 2);   // compact rows
  float*          x32  = (float*)alloc((size_t)nseed * CD * 4);
  unsigned short* wt   = (unsigned short*)alloc(2 * 32768 * 2);
  int* deg_pd   = (int*)alloc((size_t)M * 4);
  int* row_ptr  = (int*)alloc((size_t)M * 4);
  int* col      = (int*)alloc((size_t)E * 4);
  int* col2     = (int*)alloc((size_t)E * 4);
  unsigned char* inv = (unsigned char*)alloc((size_t)M);   // [p][node] flags
  int* nlist    = (int*)alloc((size_t)M * 4);
  int* cidx     = (int*)alloc((size_t)M * 4);
  int* ncnt     = (int*)alloc(256);
  int* bsums    = (int*)alloc(4096);

  int NB2 = (N + 255) / 256;               // compaction blocks
  int M2 = 4 * NB2;                        // bcnt/bexc length
  int* bcnt = (int*)alloc((size_t)M2 * 4);
  int* bexc = (int*)alloc((size_t)M2 * 4);
  (void)ws_size;

  hipMemsetAsync(deg_pd, 0, (size_t)M * 4, stream);
  hipMemsetAsync(inv, 0, (size_t)M, stream);

  int egrid = (E + 255) / 256;
  int NB = (M + 1023) / 1024;
  int NBc = (M2 + 1023) / 1024;
  int ggrid = (N + 127) / 128;

  xprep<<<(N * 16 + 255) / 256, 256, 0, stream>>>(x, x_bf, x32, nseed, N * 16);
  wprep<<<(8192 + 255) / 256, 256, 0, stream>>>(wroot, wnbr, wt, 8192);
  histk<<<egrid, 256, 0, stream>>>(ntime, eidx, deg_pd, inv, minp, up, N, E);

  // compaction: count -> scan -> scatter (+ node->gi map, + ncnt totals)
  compcnt<<<NB2, 256, 0, stream>>>(inv, bcnt, NB2, N);
  scan1<<<NBc, 256, 0, stream>>>(bcnt, bexc, bsums, M2);
  scan2<<<1, 256, 0, stream>>>(bsums, NBc);
  scan3<<<NBc, 256, 0, stream>>>(bexc, bsums, M2);
  compscat<<<NB2, 256, 0, stream>>>(inv, bcnt, bexc, nlist, cidx, ncnt, NB2, N);

  // CSR build (R10 cursor mechanism: row_ptr advances to bucket ends)
  scan1<<<NB, 256, 0, stream>>>(deg_pd, row_ptr, bsums, M);
  scan2<<<1, 256, 0, stream>>>(bsums, NB);
  scan3<<<NB, 256, 0, stream>>>(row_ptr, bsums, M);
  fillk<<<egrid, 256, 0, stream>>>(ntime, eidx, row_ptr, col, minp, up, N, E);
  remapk<<<egrid, 256, 0, stream>>>(col, col2, cidx, row_ptr, N, E);

  for (int p = 0; p < P; ++p) {
    const int* nlp = nlist + (size_t)p * N;
    const int* pc  = ncnt + p;
    gemm_fused<<<ggrid, 256, 0, stream>>>(x_bf, wt,
        bias, lng, lnb, h_bf, nullptr, nullptr, nlp, pc,
        deg_pd, row_ptr, col, p, N, 0, nseed);
    gemm_fused<<<ggrid, 256, 0, stream>>>(h_bf, wt + 32768,
        bias + CD, lng + CD, lnb + CD, nullptr, x32, x_bf, nlp, pc,
        deg_pd, row_ptr, col2, p, N, 1, nseed);
  }
  headk<<<(nseed + 3) / 4, 256, 0, stream>>>(x32, headw, headb, (float*)d_out, nseed);
}